// Round 2
// baseline (2521.300 us; speedup 1.0000x reference)
//
#include <hip/hip_runtime.h>

// VQ forward on MI355X — round 11: 2-phase pipelined coarse (T3-minimum,
// m248v2 recipe) + 4-quarter grid for 3 blocks/CU + fused rescore/epilogue.
// x: [32768,512] fp32, codebook: [8192,512] fp32.
// d_out (fp32): [16.7M) quantized_st | [1] vq_loss | [32768] idx-as-float
//
// R10 post-mortem: spills gone (WRITE 320MB->6.6MB) but all utils ~20% ->
// latency-bound: per K-step the 4 global_load_lds are drained by an
// immediate __syncthreads (vmcnt(0)) with only 8 waves/CU to hide it.
// R11: (a) double-buffered LDS, stage step s+1 at top of step s, compute
// from buf[cur], single vmcnt(0)+raw s_barrier at END of step (load latency
// hides under 8 ds_read + 16 MFMA); (b) 4 code-quarters -> grid 1024,
// launch_bounds(256,3) -> 3 blocks/CU (LDS 39.9KB, regs ~132<170);
// (c) epilogue fused into rescore (saves 64MB x re-read + 32768-block
// launch; loss reduction replicated bit-exactly as two 64-lane trees).
// MFMA K-sequence per (row,code) unchanged -> screen distances identical;
// quarter prefix-min >= half prefix-min -> candidate superset; rescore
// exact -> outputs bit-identical (absmax 0 since R1).

#define NROWS 32768
#define KCODES 8192
#define DD 512
#define CAP 12
#define MARGIN 2.5e-4f

typedef __bf16 bf16_t;
typedef __bf16 bf16x8 __attribute__((ext_vector_type(8)));
typedef float f32x4 __attribute__((ext_vector_type(4)));

// LDS layout: 16B chunk (row, slot s in 0..3) at byte row*64 + (s^((row>>1)&3))*16.
__device__ __forceinline__ int lofs(int row, int s) {
  return row * 32 + (((s ^ ((row >> 1) & 3))) << 3);   // bf16-element offset
}

__device__ __forceinline__ void gld16(const bf16_t* g, bf16_t* l) {
  __builtin_amdgcn_global_load_lds(
      (const __attribute__((address_space(1))) void*)g,
      (__attribute__((address_space(3))) void*)l, 16, 0, 0);
}

// ---------------- fused: sum of fp32 squares per row (fp64 accumulate, fp32
// round — summation order identical since R9) + bf16 convert.
__global__ __launch_bounds__(256) void prep_kernel(const float* __restrict__ in,
                                                   float* __restrict__ out_sq,
                                                   bf16_t* __restrict__ outb,
                                                   int nrows) {
  const int wave = threadIdx.x >> 6;
  const int lane = threadIdx.x & 63;
  const int row = blockIdx.x * 4 + wave;
  if (row >= nrows) return;
  const float* p = in + (size_t)row * DD;
  double s = 0.0;
#pragma unroll
  for (int j = 0; j < DD / 64; ++j) {
    float v = p[j * 64 + lane];
    float sq = v * v;
    s += (double)sq;
  }
  for (int off = 32; off > 0; off >>= 1) s += __shfl_down(s, off, 64);
  if (lane == 0) out_sq[row] = (float)s;
  const float4* p4 = (const float4*)p;
  float4 a = p4[lane * 2];
  float4 b = p4[lane * 2 + 1];
  bf16x8 o = {(bf16_t)a.x, (bf16_t)a.y, (bf16_t)a.z, (bf16_t)a.w,
              (bf16_t)b.x, (bf16_t)b.y, (bf16_t)b.z, (bf16_t)b.w};
  *(bf16x8*)(outb + (size_t)row * DD + lane * 8) = o;
}

// ---------------- coarse: bf16 MFMA GEMM (16x16x32) + prefix-min margin screen
// Block tile 128 rows x 128 codes, 4 waves each 64x64 (acc[4][4]).
// 2-phase pipeline: stage(s+1) -> ds_read/MFMA(s) -> vmcnt(0)+barrier.
__global__ __launch_bounds__(256, 3) void coarse_kernel(
    const bf16_t* __restrict__ xbf, const bf16_t* __restrict__ cbbf,
    const float* __restrict__ csq, unsigned char* __restrict__ cnt_g,
    int* __restrict__ list_g) {
  __shared__ bf16_t As[2][128 * 32];            // 16 KB (double-buffered)
  __shared__ bf16_t Bs[2][128 * 32];            // 16 KB
  __shared__ unsigned best[128];                // fp32 bits of min dist (d'>0)
  __shared__ int cnt_l[128];
  __shared__ int list_l[128 * CAP];             // 6 KB

  const int tid = threadIdx.x;
  const int w = tid >> 6;
  const int lane = tid & 63;
  const int q = lane >> 4;           // quad: k-group q*8..q*8+7, C rows q*4+reg
  const int l15 = lane & 15;
  const int rOff = (w & 1) * 64;     // wave rows rOff..rOff+63
  const int cOff = (w >> 1) * 64;    // wave cols cOff..cOff+63

  // XCD-aware decode: consecutive blockIdx round-robin XCDs (grid 1024 % 8
  // == 0). Each XCD pair owns one 2MB bf16 codebook quarter (L2-resident);
  // row-blocks contiguous per XCD.
  const int bid = blockIdx.x;
  const int xcd = bid & 7;
  const int g = bid >> 3;                    // 0..127
  const int qtr = xcd >> 1;                  // 0..3
  const int rowblk = (xcd & 1) * 128 + g;    // 0..255, bijective
  const int row0 = rowblk * 128;
  const int cbase = qtr * (KCODES / 4);
  const int NCI = (KCODES / 4) / 128;        // 16 code tiles of 128
  const int NSTEP = NCI * (DD / 32);         // 256 K-steps total

  for (int i = tid; i < 128; i += 256) { best[i] = 0xFFFFFFFFu; cnt_l[i] = 0; }

  // ---- DMA staging assignments (lane-fixed). Each gld16: 64 lanes x 16B =
  // 16 rows. lane l -> row rb+(l>>2), pos p=l&3, global slot sg=p^((row>>1)&3).
  // LDS dest = base + l*16B (contiguous in lane order: HW scatter).
  const int sub = lane >> 2;
  const int pos = lane & 3;
  const bf16_t *agp[2], *bgp[2];
  int aofs[2], bofs[2];                      // LDS element offsets (lane slot)
#pragma unroll
  for (int a = 0; a < 2; ++a) {
    const int row = w * 32 + a * 16 + sub;   // wave w stages rows w*32..+31
    const int sg = pos ^ ((row >> 1) & 3);
    agp[a] = xbf + (size_t)(row0 + row) * DD + sg * 8;
    aofs[a] = row * 32 + pos * 8;
    bgp[a] = cbbf + (size_t)(cbase + row) * DD + sg * 8;
    bofs[a] = row * 32 + pos * 8;
  }

  // fragment read offsets
  int afofs[4], bfofs[4];
#pragma unroll
  for (int rt = 0; rt < 4; ++rt) afofs[rt] = lofs(rOff + rt * 16 + l15, q);
#pragma unroll
  for (int ct = 0; ct < 4; ++ct) bfofs[ct] = lofs(cOff + ct * 16 + l15, q);

  // prologue: stage step 0 into buf 0, then full drain + barrier.
  gld16(agp[0], &As[0][aofs[0]]);
  gld16(agp[1], &As[0][aofs[1]]);
  gld16(bgp[0], &Bs[0][bofs[0]]);
  gld16(bgp[1], &Bs[0][bofs[1]]);
  __syncthreads();   // vmcnt(0) drain: buf0 ready; best/cnt init visible

  f32x4 acc[4][4];

  // One pipeline step: stage s+1 into buf[cur^1], compute buf[cur], then
  // vmcnt(0) + raw barrier. Readers of buf[cur^1] finished at step s-1
  // (lgkmcnt before MFMA precedes that step's end barrier) -> no race.
#define PIPE_STEP(S, CUR)                                                     \
  do {                                                                        \
    const int sN = (S) + 1;                                                   \
    if (sN < NSTEP) {                                                         \
      const int kbN = (sN & (DD / 32 - 1)) * 32;                              \
      const size_t coffN = (size_t)((sN >> 4) * 128) * DD;                    \
      gld16(agp[0] + kbN, &As[(CUR) ^ 1][aofs[0]]);                           \
      gld16(agp[1] + kbN, &As[(CUR) ^ 1][aofs[1]]);                           \
      gld16(bgp[0] + coffN + kbN, &Bs[(CUR) ^ 1][bofs[0]]);                   \
      gld16(bgp[1] + coffN + kbN, &Bs[(CUR) ^ 1][bofs[1]]);                   \
    }                                                                         \
    bf16x8 af[4], bfr[4];                                                     \
    _Pragma("unroll") for (int rt = 0; rt < 4; ++rt)                          \
        af[rt] = *(const bf16x8*)&As[(CUR)][afofs[rt]];                       \
    _Pragma("unroll") for (int ct = 0; ct < 4; ++ct)                          \
        bfr[ct] = *(const bf16x8*)&Bs[(CUR)][bfofs[ct]];                      \
    _Pragma("unroll") for (int rt = 0; rt < 4; ++rt)                          \
        _Pragma("unroll") for (int ct = 0; ct < 4; ++ct)                      \
            acc[rt][ct] = __builtin_amdgcn_mfma_f32_16x16x32_bf16(            \
                af[rt], bfr[ct], acc[rt][ct], 0, 0, 0);                       \
    asm volatile("s_waitcnt vmcnt(0)" ::: "memory");                          \
    __builtin_amdgcn_sched_barrier(0);                                        \
    __builtin_amdgcn_s_barrier();                                             \
    __builtin_amdgcn_sched_barrier(0);                                        \
  } while (0)

#pragma unroll 1
  for (int ci = 0; ci < NCI; ++ci) {
    const int c0 = cbase + ci * 128;
#pragma unroll
    for (int rt = 0; rt < 4; ++rt)
#pragma unroll
      for (int ct = 0; ct < 4; ++ct) {
        f32x4 z = {0.f, 0.f, 0.f, 0.f};
        acc[rt][ct] = z;
      }

    // 16 K-steps, unrolled by 2 so the buffer index is compile-time const.
#pragma unroll 1
    for (int kc2 = 0; kc2 < (DD / 32) / 2; ++kc2) {
      const int s = ci * (DD / 32) + kc2 * 2;
      PIPE_STEP(s, 0);
      PIPE_STEP(s + 1, 1);
    }

    // ---- screen this 128-code tile. d' = 1 + csq - 2*dot (>0, bit-orderable)
    float cs1[4];
#pragma unroll
    for (int ct = 0; ct < 4; ++ct)
      cs1[ct] = 1.0f + csq[c0 + cOff + ct * 16 + l15];

    // min pass (C/D layout m89: col=lane&15, row=q*4+reg)
#pragma unroll
    for (int rt = 0; rt < 4; ++rt) {
#pragma unroll
      for (int reg = 0; reg < 4; ++reg) {
        float m = fmaf(-2.0f, acc[rt][0][reg], cs1[0]);
#pragma unroll
        for (int ct = 1; ct < 4; ++ct) {
          float d = fmaf(-2.0f, acc[rt][ct][reg], cs1[ct]);
          m = fminf(m, d);
        }
        unsigned mb = __float_as_uint(m);   // d'>0 -> bit order == value order
#pragma unroll
        for (int msk = 1; msk <= 8; msk <<= 1) {
          unsigned o = __shfl_xor(mb, msk, 64);
          mb = mb < o ? mb : o;
        }
        if (l15 == 0) atomicMin(&best[rOff + rt * 16 + q * 4 + reg], mb);
      }
    }
    __syncthreads();

    // append pass vs prefix-min threshold
#pragma unroll
    for (int rt = 0; rt < 4; ++rt) {
#pragma unroll
      for (int reg = 0; reg < 4; ++reg) {
        const int rloc = rOff + rt * 16 + q * 4 + reg;
        const float thr = __uint_as_float(best[rloc]) + MARGIN;
#pragma unroll
        for (int ct = 0; ct < 4; ++ct) {
          float d = fmaf(-2.0f, acc[rt][ct][reg], cs1[ct]);
          if (d <= thr) {
            int pos2 = atomicAdd(&cnt_l[rloc], 1);
            if (pos2 < CAP)
              list_l[rloc * CAP + pos2] = c0 + cOff + ct * 16 + l15;
          }
        }
      }
    }
    __syncthreads();
  }
#undef PIPE_STEP

  // per-quarter outputs. cnt clamped to CAP+1 (overflow flag survives u8).
  for (int i = tid; i < 128; i += 256) {
    int c = cnt_l[i];
    cnt_g[(size_t)(row0 + i) * 4 + qtr] = (unsigned char)(c > CAP ? CAP + 1 : c);
  }
  for (int i = tid; i < 128 * CAP; i += 256) {
    const int r = i / CAP, p = i % CAP;
    list_g[((size_t)(row0 + r) * 4 + qtr) * CAP + p] = list_l[i];
  }
}

// ---------------- phase 2 fused: exact rescore (R1's bit-exact chain) +
// straight-through gather + loss partial + idx-as-float. One wave per row.
__global__ __launch_bounds__(256) void rescore_epilogue_kernel(
    const float* __restrict__ x, const float* __restrict__ cb,
    const float* __restrict__ xsq, const float* __restrict__ csq,
    const int* __restrict__ list, const unsigned char* __restrict__ cnt,
    float* __restrict__ out_q, float* __restrict__ out_idx_f,
    double* __restrict__ partials) {
  const int row = blockIdx.x * 4 + (threadIdx.x >> 6);
  const int lane = threadIdx.x & 63;
  const unsigned char* c4 = cnt + (size_t)row * 4;
  const int n0 = c4[0], n1 = c4[1], n2 = c4[2], n3 = c4[3];
  const int t0 = n0, t1 = t0 + n1, t2 = t1 + n2, t3 = t2 + n3;
  const float xs = xsq[row];
  const float4* xr4 = (const float4*)(x + (size_t)row * DD);
  unsigned long long bestv = ~0ULL;

  if (n0 <= CAP && n1 <= CAP && n2 <= CAP && n3 <= CAP && t3 >= 1) {
    int myidx = -1;
    if (lane < t3) {
      int seg, off;
      if (lane < t0)      { seg = 0; off = lane; }
      else if (lane < t1) { seg = 1; off = lane - t0; }
      else if (lane < t2) { seg = 2; off = lane - t1; }
      else                { seg = 3; off = lane - t2; }
      myidx = list[((size_t)row * 4 + seg) * CAP + off];
    }
    if (myidx >= 0) {
      const float4* cr4 = (const float4*)(cb + (size_t)myidx * DD);
      float acc = 0.0f;
      for (int k4 = 0; k4 < DD / 4; ++k4) {     // sequential ascending k: R1 order
        float4 xv = xr4[k4];
        float4 cv = cr4[k4];
        acc = fmaf(xv.x, cv.x, acc);
        acc = fmaf(xv.y, cv.y, acc);
        acc = fmaf(xv.z, cv.z, acc);
        acc = fmaf(xv.w, cv.w, acc);
      }
      float t = xs - 2.0f * acc;
      float d = t + csq[myidx];
      bestv = ((unsigned long long)__float_as_uint(d) << 32) | (unsigned)myidx;
    }
  } else {
    // safety fallback: full exact scan
    for (int idx = lane; idx < KCODES; idx += 64) {
      const float4* cr4 = (const float4*)(cb + (size_t)idx * DD);
      float acc = 0.0f;
      for (int k4 = 0; k4 < DD / 4; ++k4) {
        float4 xv = xr4[k4];
        float4 cv = cr4[k4];
        acc = fmaf(xv.x, cv.x, acc);
        acc = fmaf(xv.y, cv.y, acc);
        acc = fmaf(xv.z, cv.z, acc);
        acc = fmaf(xv.w, cv.w, acc);
      }
      float t = xs - 2.0f * acc;
      float d = t + csq[idx];
      unsigned long long pk =
          ((unsigned long long)__float_as_uint(d) << 32) | (unsigned)idx;
      if (pk < bestv) bestv = pk;
    }
  }
#pragma unroll
  for (int s = 1; s <= 32; s <<= 1) {
    unsigned long long o = __shfl_xor(bestv, s, 64);
    if (o < bestv) bestv = o;
  }
  const int k = (int)(bestv & 0xffffffffu);

  // ---- fused epilogue. Bit-exact replica of the old 128-thread kernel:
  // lane handles float4 #lane (old wave0 thread) and #lane+64 (old wave1),
  // reduced as two independent 64-lane shuffle trees, summed at the end.
  const float4* qr = (const float4*)(cb + (size_t)k * DD);
  float4* orow = (float4*)(out_q + (size_t)row * DD);

  float4 xa = xr4[lane], qa = qr[lane];
  float dax = qa.x - xa.x, day = qa.y - xa.y, daz = qa.z - xa.z, daw = qa.w - xa.w;
  float4 oa;
  oa.x = xa.x + dax; oa.y = xa.y + day; oa.z = xa.z + daz; oa.w = xa.w + daw;
  orow[lane] = oa;
  double pa = (double)(dax * dax) + (double)(day * day) +
              (double)(daz * daz) + (double)(daw * daw);

  float4 xb = xr4[lane + 64], qb = qr[lane + 64];
  float dbx = qb.x - xb.x, dby = qb.y - xb.y, dbz = qb.z - xb.z, dbw = qb.w - xb.w;
  float4 ob;
  ob.x = xb.x + dbx; ob.y = xb.y + dby; ob.z = xb.z + dbz; ob.w = xb.w + dbw;
  orow[lane + 64] = ob;
  double pb = (double)(dbx * dbx) + (double)(dby * dby) +
              (double)(dbz * dbz) + (double)(dbw * dbw);

  for (int off = 32; off > 0; off >>= 1) pa += __shfl_down(pa, off, 64);
  for (int off = 32; off > 0; off >>= 1) pb += __shfl_down(pb, off, 64);
  if (lane == 0) {
    partials[row] = pa + pb;
    out_idx_f[row] = (float)k;
  }
}

// ---------------- reduce partials -> vq_loss
__global__ __launch_bounds__(256) void finalize_kernel(
    const double* __restrict__ partials, float* __restrict__ out_loss) {
  __shared__ double red[256];
  double s = 0.0;
  for (int i = threadIdx.x; i < NROWS; i += 256) s += partials[i];
  red[threadIdx.x] = s;
  __syncthreads();
  for (int st = 128; st > 0; st >>= 1) {
    if (threadIdx.x < st) red[threadIdx.x] += red[threadIdx.x + st];
    __syncthreads();
  }
  if (threadIdx.x == 0) {
    double mean = red[0] / ((double)NROWS * (double)DD);
    float cl = (float)mean;
    out_loss[0] = cl + 0.25f * cl;
  }
}

extern "C" void kernel_launch(void* const* d_in, const int* in_sizes, int n_in,
                              void* d_out, int out_size, void* d_ws,
                              size_t ws_size, hipStream_t stream) {
  const float* x = (const float*)d_in[0];
  const float* cb = (const float*)d_in[1];
  float* out = (float*)d_out;

  // ws layout: partials | csq | xsq | cnt(u8, 4/row) | list(4 qtr x CAP/row)
  char* ws = (char*)d_ws;
  double* partials = (double*)ws;                               // 262144 B
  float* csq = (float*)(ws + 262144);                           //  32768 B
  float* xsq = (float*)(ws + 262144 + 32768);                   // 131072 B
  unsigned char* cnt = (unsigned char*)(ws + 262144 + 32768 + 131072); // 131072 B
  int* list = (int*)(ws + 262144 + 32768 + 131072 + 131072);    // 6291456 B

  // bf16 copies live in d_out scratch (overwritten by fused epilogue later)
  bf16_t* cbbf = (bf16_t*)d_out;
  bf16_t* xbf = cbbf + (size_t)KCODES * DD;

  prep_kernel<<<KCODES / 4, 256, 0, stream>>>(cb, csq, cbbf, KCODES);
  prep_kernel<<<NROWS / 4, 256, 0, stream>>>(x, xsq, xbf, NROWS);
  coarse_kernel<<<1024, 256, 0, stream>>>(xbf, cbbf, csq, cnt, list);
  rescore_epilogue_kernel<<<NROWS / 4, 256, 0, stream>>>(
      x, cb, xsq, csq, list, cnt, out, out + 16777216 + 1, partials);
  finalize_kernel<<<1, 256, 0, stream>>>(partials, out + 16777216);
}

// Round 3
// 1009.678 us; speedup vs baseline: 2.4971x; 2.4971x over previous
//
#include <hip/hip_runtime.h>

// VQ forward on MI355X — round 12: fix the R11 rescore straggler tail.
// x: [32768,512] fp32, codebook: [8192,512] fp32.
// d_out (fp32): [16.7M) quantized_st | [1] vq_loss | [32768] idx-as-float
//
// R11 post-mortem: coarse improved (left top-5) but rescore_epilogue blew up
// to ~2030us with occupancy 10% / VALU 2.3% / FETCH 540MB: CAP 12 per
// quarter overflowed on ~25 rows -> full 8192-code uncoalesced fallback
// scans (~16k scattered 16B gathers per wave) serialized as a tail.
// R12: (a) CAP 24/quarter with u16 code ids (ws footprint unchanged,
// overflow ~never); (b) fallback restricted to the overflowed quarter(s)
// only (2048 codes), merged with listed candidates from healthy quarters;
// full scan only if >64 total listed (needs 65+ near-min ties). Exact
// rescore chain (R1 fmaf order) identical in all paths; packed (dist,idx)
// min = lowest-index tie-break = jnp.argmin. Candidate sets are supersets
// of R11's -> outputs bit-identical (absmax 0 since R1). Coarse unchanged.

#define NROWS 32768
#define KCODES 8192
#define DD 512
#define CAP 24
#define MARGIN 2.5e-4f

typedef __bf16 bf16_t;
typedef __bf16 bf16x8 __attribute__((ext_vector_type(8)));
typedef float f32x4 __attribute__((ext_vector_type(4)));

// LDS layout: 16B chunk (row, slot s in 0..3) at byte row*64 + (s^((row>>1)&3))*16.
__device__ __forceinline__ int lofs(int row, int s) {
  return row * 32 + (((s ^ ((row >> 1) & 3))) << 3);   // bf16-element offset
}

__device__ __forceinline__ void gld16(const bf16_t* g, bf16_t* l) {
  __builtin_amdgcn_global_load_lds(
      (const __attribute__((address_space(1))) void*)g,
      (__attribute__((address_space(3))) void*)l, 16, 0, 0);
}

// ---------------- fused: sum of fp32 squares per row (fp64 accumulate, fp32
// round — summation order identical since R9) + bf16 convert.
__global__ __launch_bounds__(256) void prep_kernel(const float* __restrict__ in,
                                                   float* __restrict__ out_sq,
                                                   bf16_t* __restrict__ outb,
                                                   int nrows) {
  const int wave = threadIdx.x >> 6;
  const int lane = threadIdx.x & 63;
  const int row = blockIdx.x * 4 + wave;
  if (row >= nrows) return;
  const float* p = in + (size_t)row * DD;
  double s = 0.0;
#pragma unroll
  for (int j = 0; j < DD / 64; ++j) {
    float v = p[j * 64 + lane];
    float sq = v * v;
    s += (double)sq;
  }
  for (int off = 32; off > 0; off >>= 1) s += __shfl_down(s, off, 64);
  if (lane == 0) out_sq[row] = (float)s;
  const float4* p4 = (const float4*)p;
  float4 a = p4[lane * 2];
  float4 b = p4[lane * 2 + 1];
  bf16x8 o = {(bf16_t)a.x, (bf16_t)a.y, (bf16_t)a.z, (bf16_t)a.w,
              (bf16_t)b.x, (bf16_t)b.y, (bf16_t)b.z, (bf16_t)b.w};
  *(bf16x8*)(outb + (size_t)row * DD + lane * 8) = o;
}

// ---------------- coarse: bf16 MFMA GEMM (16x16x32) + prefix-min margin screen
// Block tile 128 rows x 128 codes, 4 waves each 64x64 (acc[4][4]).
// 2-phase pipeline: stage(s+1) -> ds_read/MFMA(s) -> vmcnt(0)+barrier.
__global__ __launch_bounds__(256, 3) void coarse_kernel(
    const bf16_t* __restrict__ xbf, const bf16_t* __restrict__ cbbf,
    const float* __restrict__ csq, unsigned char* __restrict__ cnt_g,
    unsigned short* __restrict__ list_g) {
  __shared__ bf16_t As[2][128 * 32];            // 16 KB (double-buffered)
  __shared__ bf16_t Bs[2][128 * 32];            // 16 KB
  __shared__ unsigned best[128];                // fp32 bits of min dist (d'>0)
  __shared__ int cnt_l[128];
  __shared__ int list_l[128 * CAP];             // 12 KB

  const int tid = threadIdx.x;
  const int w = tid >> 6;
  const int lane = tid & 63;
  const int q = lane >> 4;           // quad: k-group q*8..q*8+7, C rows q*4+reg
  const int l15 = lane & 15;
  const int rOff = (w & 1) * 64;     // wave rows rOff..rOff+63
  const int cOff = (w >> 1) * 64;    // wave cols cOff..cOff+63

  // XCD-aware decode: consecutive blockIdx round-robin XCDs (grid 1024 % 8
  // == 0). Each XCD pair owns one 2MB bf16 codebook quarter (L2-resident);
  // row-blocks contiguous per XCD.
  const int bid = blockIdx.x;
  const int xcd = bid & 7;
  const int g = bid >> 3;                    // 0..127
  const int qtr = xcd >> 1;                  // 0..3
  const int rowblk = (xcd & 1) * 128 + g;    // 0..255, bijective
  const int row0 = rowblk * 128;
  const int cbase = qtr * (KCODES / 4);
  const int NCI = (KCODES / 4) / 128;        // 16 code tiles of 128
  const int NSTEP = NCI * (DD / 32);         // 256 K-steps total

  for (int i = tid; i < 128; i += 256) { best[i] = 0xFFFFFFFFu; cnt_l[i] = 0; }

  // ---- DMA staging assignments (lane-fixed). Each gld16: 64 lanes x 16B =
  // 16 rows. lane l -> row rb+(l>>2), pos p=l&3, global slot sg=p^((row>>1)&3).
  // LDS dest = base + l*16B (contiguous in lane order: HW scatter).
  const int sub = lane >> 2;
  const int pos = lane & 3;
  const bf16_t *agp[2], *bgp[2];
  int aofs[2], bofs[2];                      // LDS element offsets (lane slot)
#pragma unroll
  for (int a = 0; a < 2; ++a) {
    const int row = w * 32 + a * 16 + sub;   // wave w stages rows w*32..+31
    const int sg = pos ^ ((row >> 1) & 3);
    agp[a] = xbf + (size_t)(row0 + row) * DD + sg * 8;
    aofs[a] = row * 32 + pos * 8;
    bgp[a] = cbbf + (size_t)(cbase + row) * DD + sg * 8;
    bofs[a] = row * 32 + pos * 8;
  }

  // fragment read offsets
  int afofs[4], bfofs[4];
#pragma unroll
  for (int rt = 0; rt < 4; ++rt) afofs[rt] = lofs(rOff + rt * 16 + l15, q);
#pragma unroll
  for (int ct = 0; ct < 4; ++ct) bfofs[ct] = lofs(cOff + ct * 16 + l15, q);

  // prologue: stage step 0 into buf 0, then full drain + barrier.
  gld16(agp[0], &As[0][aofs[0]]);
  gld16(agp[1], &As[0][aofs[1]]);
  gld16(bgp[0], &Bs[0][bofs[0]]);
  gld16(bgp[1], &Bs[0][bofs[1]]);
  __syncthreads();   // vmcnt(0) drain: buf0 ready; best/cnt init visible

  f32x4 acc[4][4];

  // One pipeline step: stage s+1 into buf[cur^1], compute buf[cur], then
  // vmcnt(0) + raw barrier. Readers of buf[cur^1] finished at step s-1
  // (lgkmcnt before MFMA precedes that step's end barrier) -> no race.
#define PIPE_STEP(S, CUR)                                                     \
  do {                                                                        \
    const int sN = (S) + 1;                                                   \
    if (sN < NSTEP) {                                                         \
      const int kbN = (sN & (DD / 32 - 1)) * 32;                              \
      const size_t coffN = (size_t)((sN >> 4) * 128) * DD;                    \
      gld16(agp[0] + kbN, &As[(CUR) ^ 1][aofs[0]]);                           \
      gld16(agp[1] + kbN, &As[(CUR) ^ 1][aofs[1]]);                           \
      gld16(bgp[0] + coffN + kbN, &Bs[(CUR) ^ 1][bofs[0]]);                   \
      gld16(bgp[1] + coffN + kbN, &Bs[(CUR) ^ 1][bofs[1]]);                   \
    }                                                                         \
    bf16x8 af[4], bfr[4];                                                     \
    _Pragma("unroll") for (int rt = 0; rt < 4; ++rt)                          \
        af[rt] = *(const bf16x8*)&As[(CUR)][afofs[rt]];                       \
    _Pragma("unroll") for (int ct = 0; ct < 4; ++ct)                          \
        bfr[ct] = *(const bf16x8*)&Bs[(CUR)][bfofs[ct]];                      \
    _Pragma("unroll") for (int rt = 0; rt < 4; ++rt)                          \
        _Pragma("unroll") for (int ct = 0; ct < 4; ++ct)                      \
            acc[rt][ct] = __builtin_amdgcn_mfma_f32_16x16x32_bf16(            \
                af[rt], bfr[ct], acc[rt][ct], 0, 0, 0);                       \
    asm volatile("s_waitcnt vmcnt(0)" ::: "memory");                          \
    __builtin_amdgcn_sched_barrier(0);                                        \
    __builtin_amdgcn_s_barrier();                                             \
    __builtin_amdgcn_sched_barrier(0);                                        \
  } while (0)

#pragma unroll 1
  for (int ci = 0; ci < NCI; ++ci) {
    const int c0 = cbase + ci * 128;
#pragma unroll
    for (int rt = 0; rt < 4; ++rt)
#pragma unroll
      for (int ct = 0; ct < 4; ++ct) {
        f32x4 z = {0.f, 0.f, 0.f, 0.f};
        acc[rt][ct] = z;
      }

    // 16 K-steps, unrolled by 2 so the buffer index is compile-time const.
#pragma unroll 1
    for (int kc2 = 0; kc2 < (DD / 32) / 2; ++kc2) {
      const int s = ci * (DD / 32) + kc2 * 2;
      PIPE_STEP(s, 0);
      PIPE_STEP(s + 1, 1);
    }

    // ---- screen this 128-code tile. d' = 1 + csq - 2*dot (>0, bit-orderable)
    float cs1[4];
#pragma unroll
    for (int ct = 0; ct < 4; ++ct)
      cs1[ct] = 1.0f + csq[c0 + cOff + ct * 16 + l15];

    // min pass (C/D layout m89: col=lane&15, row=q*4+reg)
#pragma unroll
    for (int rt = 0; rt < 4; ++rt) {
#pragma unroll
      for (int reg = 0; reg < 4; ++reg) {
        float m = fmaf(-2.0f, acc[rt][0][reg], cs1[0]);
#pragma unroll
        for (int ct = 1; ct < 4; ++ct) {
          float d = fmaf(-2.0f, acc[rt][ct][reg], cs1[ct]);
          m = fminf(m, d);
        }
        unsigned mb = __float_as_uint(m);   // d'>0 -> bit order == value order
#pragma unroll
        for (int msk = 1; msk <= 8; msk <<= 1) {
          unsigned o = __shfl_xor(mb, msk, 64);
          mb = mb < o ? mb : o;
        }
        if (l15 == 0) atomicMin(&best[rOff + rt * 16 + q * 4 + reg], mb);
      }
    }
    __syncthreads();

    // append pass vs prefix-min threshold
#pragma unroll
    for (int rt = 0; rt < 4; ++rt) {
#pragma unroll
      for (int reg = 0; reg < 4; ++reg) {
        const int rloc = rOff + rt * 16 + q * 4 + reg;
        const float thr = __uint_as_float(best[rloc]) + MARGIN;
#pragma unroll
        for (int ct = 0; ct < 4; ++ct) {
          float d = fmaf(-2.0f, acc[rt][ct][reg], cs1[ct]);
          if (d <= thr) {
            int pos2 = atomicAdd(&cnt_l[rloc], 1);
            if (pos2 < CAP)
              list_l[rloc * CAP + pos2] = c0 + cOff + ct * 16 + l15;
          }
        }
      }
    }
    __syncthreads();
  }
#undef PIPE_STEP

  // per-quarter outputs. cnt clamped to CAP+1 (overflow flag survives u8).
  for (int i = tid; i < 128; i += 256) {
    int c = cnt_l[i];
    cnt_g[(size_t)(row0 + i) * 4 + qtr] = (unsigned char)(c > CAP ? CAP + 1 : c);
  }
  for (int i = tid; i < 128 * CAP; i += 256) {
    const int r = i / CAP, p = i % CAP;
    list_g[((size_t)(row0 + r) * 4 + qtr) * CAP + p] =
        (unsigned short)list_l[i];
  }
}

// ---------------- exact distance, R1's bit-exact fmaf chain (both paths)
__device__ __forceinline__ float exact_dist(const float4* __restrict__ xr4,
                                            const float* __restrict__ cb,
                                            const float* __restrict__ csq,
                                            float xs, int idx) {
  const float4* cr4 = (const float4*)(cb + (size_t)idx * DD);
  float acc = 0.0f;
  for (int k4 = 0; k4 < DD / 4; ++k4) {     // sequential ascending k: R1 order
    float4 xv = xr4[k4];
    float4 cv = cr4[k4];
    acc = fmaf(xv.x, cv.x, acc);
    acc = fmaf(xv.y, cv.y, acc);
    acc = fmaf(xv.z, cv.z, acc);
    acc = fmaf(xv.w, cv.w, acc);
  }
  float t = xs - 2.0f * acc;
  return t + csq[idx];
}

// ---------------- phase 2 fused: exact rescore + straight-through gather +
// loss partial + idx-as-float. One wave per row. Overflowed quarters (count
// > CAP, ~never at CAP 24) are exactly scanned (2048 codes, 32/lane) instead
// of a full 8192-code scan — kills the R11 straggler tail.
__global__ __launch_bounds__(256) void rescore_epilogue_kernel(
    const float* __restrict__ x, const float* __restrict__ cb,
    const float* __restrict__ xsq, const float* __restrict__ csq,
    const unsigned short* __restrict__ list,
    const unsigned char* __restrict__ cnt, float* __restrict__ out_q,
    float* __restrict__ out_idx_f, double* __restrict__ partials) {
  const int row = blockIdx.x * 4 + (threadIdx.x >> 6);
  const int lane = threadIdx.x & 63;
  const unsigned char* c4 = cnt + (size_t)row * 4;
  const float xs = xsq[row];
  const float4* xr4 = (const float4*)(x + (size_t)row * DD);

  int n[4];
  bool ok[4];
  int L = 0;
#pragma unroll
  for (int s = 0; s < 4; ++s) {
    n[s] = c4[s];
    ok[s] = (n[s] <= CAP);
    if (ok[s]) L += n[s];
  }
  if (L > 64 || L == 0) {   // pathological: scan all quarters exactly
#pragma unroll
    for (int s = 0; s < 4; ++s) ok[s] = false;
    L = 0;
  }

  unsigned long long bestv = ~0ULL;

  // listed candidates from healthy quarters (lane-parallel, <=64 total)
  int myidx = -1;
  int base = 0;
#pragma unroll
  for (int s = 0; s < 4; ++s) {
    if (ok[s]) {
      if (myidx < 0 && lane >= base && lane < base + n[s])
        myidx = (int)list[((size_t)row * 4 + s) * CAP + (lane - base)];
      base += n[s];
    }
  }
  if (myidx >= 0) {
    float d = exact_dist(xr4, cb, csq, xs, myidx);
    bestv = ((unsigned long long)__float_as_uint(d) << 32) | (unsigned)myidx;
  }

  // overflowed quarters: exact lane-strided scan of that quarter only
#pragma unroll
  for (int s = 0; s < 4; ++s) {
    if (!ok[s]) {
      const int q0 = s * (KCODES / 4);
      for (int idx = q0 + lane; idx < q0 + KCODES / 4; idx += 64) {
        float d = exact_dist(xr4, cb, csq, xs, idx);
        unsigned long long pk =
            ((unsigned long long)__float_as_uint(d) << 32) | (unsigned)idx;
        if (pk < bestv) bestv = pk;
      }
    }
  }

#pragma unroll
  for (int s = 1; s <= 32; s <<= 1) {
    unsigned long long o = __shfl_xor(bestv, s, 64);
    if (o < bestv) bestv = o;
  }
  const int k = (int)(bestv & 0xffffffffu);

  // ---- fused epilogue. Bit-exact replica of the old 128-thread kernel:
  // lane handles float4 #lane (old wave0 thread) and #lane+64 (old wave1),
  // reduced as two independent 64-lane shuffle trees, summed at the end.
  const float4* qr = (const float4*)(cb + (size_t)k * DD);
  float4* orow = (float4*)(out_q + (size_t)row * DD);

  float4 xa = xr4[lane], qa = qr[lane];
  float dax = qa.x - xa.x, day = qa.y - xa.y, daz = qa.z - xa.z, daw = qa.w - xa.w;
  float4 oa;
  oa.x = xa.x + dax; oa.y = xa.y + day; oa.z = xa.z + daz; oa.w = xa.w + daw;
  orow[lane] = oa;
  double pa = (double)(dax * dax) + (double)(day * day) +
              (double)(daz * daz) + (double)(daw * daw);

  float4 xb = xr4[lane + 64], qb = qr[lane + 64];
  float dbx = qb.x - xb.x, dby = qb.y - xb.y, dbz = qb.z - xb.z, dbw = qb.w - xb.w;
  float4 ob;
  ob.x = xb.x + dbx; ob.y = xb.y + dby; ob.z = xb.z + dbz; ob.w = xb.w + dbw;
  orow[lane + 64] = ob;
  double pb = (double)(dbx * dbx) + (double)(dby * dby) +
              (double)(dbz * dbz) + (double)(dbw * dbw);

  for (int off = 32; off > 0; off >>= 1) pa += __shfl_down(pa, off, 64);
  for (int off = 32; off > 0; off >>= 1) pb += __shfl_down(pb, off, 64);
  if (lane == 0) {
    partials[row] = pa + pb;
    out_idx_f[row] = (float)k;
  }
}

// ---------------- reduce partials -> vq_loss
__global__ __launch_bounds__(256) void finalize_kernel(
    const double* __restrict__ partials, float* __restrict__ out_loss) {
  __shared__ double red[256];
  double s = 0.0;
  for (int i = threadIdx.x; i < NROWS; i += 256) s += partials[i];
  red[threadIdx.x] = s;
  __syncthreads();
  for (int st = 128; st > 0; st >>= 1) {
    if (threadIdx.x < st) red[threadIdx.x] += red[threadIdx.x + st];
    __syncthreads();
  }
  if (threadIdx.x == 0) {
    double mean = red[0] / ((double)NROWS * (double)DD);
    float cl = (float)mean;
    out_loss[0] = cl + 0.25f * cl;
  }
}

extern "C" void kernel_launch(void* const* d_in, const int* in_sizes, int n_in,
                              void* d_out, int out_size, void* d_ws,
                              size_t ws_size, hipStream_t stream) {
  const float* x = (const float*)d_in[0];
  const float* cb = (const float*)d_in[1];
  float* out = (float*)d_out;

  // ws layout: partials | csq | xsq | cnt(u8, 4/row) | list(u16, 4xCAP/row)
  char* ws = (char*)d_ws;
  double* partials = (double*)ws;                               // 262144 B
  float* csq = (float*)(ws + 262144);                           //  32768 B
  float* xsq = (float*)(ws + 262144 + 32768);                   // 131072 B
  unsigned char* cnt = (unsigned char*)(ws + 262144 + 32768 + 131072); // 131072 B
  unsigned short* list =
      (unsigned short*)(ws + 262144 + 32768 + 131072 + 131072); // 6291456 B

  // bf16 copies live in d_out scratch (overwritten by fused epilogue later)
  bf16_t* cbbf = (bf16_t*)d_out;
  bf16_t* xbf = cbbf + (size_t)KCODES * DD;

  prep_kernel<<<KCODES / 4, 256, 0, stream>>>(cb, csq, cbbf, KCODES);
  prep_kernel<<<NROWS / 4, 256, 0, stream>>>(x, xsq, xbf, NROWS);
  coarse_kernel<<<1024, 256, 0, stream>>>(xbf, cbbf, csq, cnt, list);
  rescore_epilogue_kernel<<<NROWS / 4, 256, 0, stream>>>(
      x, cb, xsq, csq, list, cnt, out, out + 16777216 + 1, partials);
  finalize_kernel<<<1, 256, 0, stream>>>(partials, out + 16777216);
}

// Round 4
// 1006.713 us; speedup vs baseline: 2.5045x; 1.0029x over previous
//
#include <hip/hip_runtime.h>

// VQ forward on MI355X — round 13: depth-3 counted-vmcnt pipeline (T4) in
// coarse + quarter-pruned rescore.
// x: [32768,512] fp32, codebook: [8192,512] fp32.
// d_out (fp32): [16.7M) quantized_st | [1] vq_loss | [32768] idx-as-float
//
// R12 post-mortem: 2-phase pipeline REGRESSED coarse (593 vs R10's 540) —
// staged loads got only ~80cy of MFMA cover before vmcnt(0), < L2 latency,
// so all 256 K-steps still drain-stall (m233's 72% overhead). R13 coarse:
// 4 LDS buffers (step&3), issue step s+3 at top of step s, s_waitcnt
// vmcnt(8) (never 0) + raw s_barrier per step; screen uses lgkmcnt(0)-only
// barriers so prefetch stays in flight across it. Phantom issues past step
// 255 wrap ci mod 16 (in-bounds, never read). Per-wave vmcnt: a wave's own
// s+1 loads drain before it passes barrier-s => once ANY wave passes, ALL
// s+1 DMA slots have landed (each wave writes its own slots) — m201's
// argument. Rescore: coarse exports per-quarter bf16 min; quarters with
// qmin > gmin+MARGIN are skipped (cannot hold argmin or exact ties, same
// MARGIN>=2eps invariant the screen uses) -> ~4x fewer candidate gathers.
// MFMA K-sequence per (row,code) unchanged; candidate set still a superset
// containing argmin+ties; exact rescore chain unchanged (absmax 0 since R1).

#define NROWS 32768
#define KCODES 8192
#define DD 512
#define CAP 24
#define MARGIN 2.5e-4f

typedef __bf16 bf16_t;
typedef __bf16 bf16x8 __attribute__((ext_vector_type(8)));
typedef float f32x4 __attribute__((ext_vector_type(4)));

// LDS layout: 16B chunk (row, slot s in 0..3) at byte row*64 + (s^((row>>1)&3))*16.
__device__ __forceinline__ int lofs(int row, int s) {
  return row * 32 + (((s ^ ((row >> 1) & 3))) << 3);   // bf16-element offset
}

__device__ __forceinline__ void gld16(const bf16_t* g, bf16_t* l) {
  __builtin_amdgcn_global_load_lds(
      (const __attribute__((address_space(1))) void*)g,
      (__attribute__((address_space(3))) void*)l, 16, 0, 0);
}

// ---------------- fused: sum of fp32 squares per row (fp64 accumulate, fp32
// round — summation order identical since R9) + bf16 convert.
__global__ __launch_bounds__(256) void prep_kernel(const float* __restrict__ in,
                                                   float* __restrict__ out_sq,
                                                   bf16_t* __restrict__ outb,
                                                   int nrows) {
  const int wave = threadIdx.x >> 6;
  const int lane = threadIdx.x & 63;
  const int row = blockIdx.x * 4 + wave;
  if (row >= nrows) return;
  const float* p = in + (size_t)row * DD;
  double s = 0.0;
#pragma unroll
  for (int j = 0; j < DD / 64; ++j) {
    float v = p[j * 64 + lane];
    float sq = v * v;
    s += (double)sq;
  }
  for (int off = 32; off > 0; off >>= 1) s += __shfl_down(s, off, 64);
  if (lane == 0) out_sq[row] = (float)s;
  const float4* p4 = (const float4*)p;
  float4 a = p4[lane * 2];
  float4 b = p4[lane * 2 + 1];
  bf16x8 o = {(bf16_t)a.x, (bf16_t)a.y, (bf16_t)a.z, (bf16_t)a.w,
              (bf16_t)b.x, (bf16_t)b.y, (bf16_t)b.z, (bf16_t)b.w};
  *(bf16x8*)(outb + (size_t)row * DD + lane * 8) = o;
}

// ---------------- coarse: bf16 MFMA GEMM (16x16x32) + prefix-min margin screen
// Block tile 128 rows x 128 codes, 4 waves each 64x64 (acc[4][4]).
// Depth-3 pipeline: issue(s+3) -> ds_read/MFMA(s) -> vmcnt(8) -> barrier.
__global__ __launch_bounds__(256, 2) void coarse_kernel(
    const bf16_t* __restrict__ xbf, const bf16_t* __restrict__ cbbf,
    const float* __restrict__ csq, unsigned char* __restrict__ cnt_g,
    unsigned short* __restrict__ list_g, unsigned* __restrict__ bmin_g) {
  __shared__ bf16_t As[4][128 * 32];            // 32 KB (4-deep ring)
  __shared__ bf16_t Bs[4][128 * 32];            // 32 KB
  __shared__ unsigned best[128];                // fp32 bits of min dist (d'>0)
  __shared__ int cnt_l[128];
  __shared__ unsigned short list_l[128 * CAP];  // 6 KB

  const int tid = threadIdx.x;
  const int w = tid >> 6;
  const int lane = tid & 63;
  const int q = lane >> 4;           // quad: k-group q*8..q*8+7, C rows q*4+reg
  const int l15 = lane & 15;
  const int rOff = (w & 1) * 64;     // wave rows rOff..rOff+63
  const int cOff = (w >> 1) * 64;    // wave cols cOff..cOff+63

  // XCD-aware decode: consecutive blockIdx round-robin XCDs (grid 1024 % 8
  // == 0). Each XCD pair owns one 2MB bf16 codebook quarter (L2-resident).
  const int bid = blockIdx.x;
  const int xcd = bid & 7;
  const int g = bid >> 3;                    // 0..127
  const int qtr = xcd >> 1;                  // 0..3
  const int rowblk = (xcd & 1) * 128 + g;    // 0..255, bijective
  const int row0 = rowblk * 128;
  const int cbase = qtr * (KCODES / 4);
  const int NCI = (KCODES / 4) / 128;        // 16 code tiles of 128

  for (int i = tid; i < 128; i += 256) { best[i] = 0xFFFFFFFFu; cnt_l[i] = 0; }

  // ---- DMA staging assignments (lane-fixed). Each gld16: 64 lanes x 16B =
  // 16 rows. lane l -> row rb+(l>>2), pos p=l&3, global slot sg=p^((row>>1)&3).
  // LDS dest = base + l*16B (contiguous in lane order: HW scatter).
  const int sub = lane >> 2;
  const int pos = lane & 3;
  const bf16_t *agp[2], *bgp[2];
  int aofs[2], bofs[2];                      // LDS element offsets (lane slot)
#pragma unroll
  for (int a = 0; a < 2; ++a) {
    const int row = w * 32 + a * 16 + sub;   // wave w stages rows w*32..+31
    const int sg = pos ^ ((row >> 1) & 3);
    agp[a] = xbf + (size_t)(row0 + row) * DD + sg * 8;
    aofs[a] = row * 32 + pos * 8;
    bgp[a] = cbbf + (size_t)(cbase + row) * DD + sg * 8;
    bofs[a] = row * 32 + pos * 8;
  }

  // fragment read offsets
  int afofs[4], bfofs[4];
#pragma unroll
  for (int rt = 0; rt < 4; ++rt) afofs[rt] = lofs(rOff + rt * 16 + l15, q);
#pragma unroll
  for (int ct = 0; ct < 4; ++ct) bfofs[ct] = lofs(cOff + ct * 16 + l15, q);

  // Issue the 4 DMA loads for global K-step sN into ring buffer `buf`.
  // Steps past the end wrap ci mod NCI: always in-bounds, never read.
  auto issue_step = [&](int sN, int buf) {
    const int kbN = (sN & (DD / 32 - 1)) * 32;
    const size_t coffN = (size_t)((sN >> 4) & (NCI - 1)) * (128 * DD);
    gld16(agp[0] + kbN, &As[buf][aofs[0]]);
    gld16(agp[1] + kbN, &As[buf][aofs[1]]);
    gld16(bgp[0] + coffN + kbN, &Bs[buf][bofs[0]]);
    gld16(bgp[1] + coffN + kbN, &Bs[buf][bofs[1]]);
  };

  // prologue: issue steps 0,1,2; wait step0 (8 newer loads may fly); barrier
  // also publishes best/cnt init (lgkmcnt(0)).
  issue_step(0, 0);
  issue_step(1, 1);
  issue_step(2, 2);
  asm volatile("s_waitcnt vmcnt(8) lgkmcnt(0)" ::: "memory");
  __builtin_amdgcn_sched_barrier(0);
  __builtin_amdgcn_s_barrier();
  __builtin_amdgcn_sched_barrier(0);

  f32x4 acc[4][4];

  // One step: issue s+3 into buf[(J+3)&3], compute buf[J], vmcnt(8) (s+1's
  // loads drained, s+2/s+3 in flight), raw barrier. Buffer (J+3)&3 was last
  // read at step s-1, whose reads drained (lgkmcnt) before barrier s-1.
#define PIPE_STEP(S, J)                                                       \
  do {                                                                        \
    issue_step((S) + 3, ((J) + 3) & 3);                                       \
    bf16x8 af[4], bfr[4];                                                     \
    _Pragma("unroll") for (int rt = 0; rt < 4; ++rt)                          \
        af[rt] = *(const bf16x8*)&As[(J)][afofs[rt]];                         \
    _Pragma("unroll") for (int ct = 0; ct < 4; ++ct)                          \
        bfr[ct] = *(const bf16x8*)&Bs[(J)][bfofs[ct]];                        \
    _Pragma("unroll") for (int rt = 0; rt < 4; ++rt)                          \
        _Pragma("unroll") for (int ct = 0; ct < 4; ++ct)                      \
            acc[rt][ct] = __builtin_amdgcn_mfma_f32_16x16x32_bf16(            \
                af[rt], bfr[ct], acc[rt][ct], 0, 0, 0);                       \
    asm volatile("s_waitcnt vmcnt(8)" ::: "memory");                          \
    __builtin_amdgcn_sched_barrier(0);                                        \
    __builtin_amdgcn_s_barrier();                                             \
    __builtin_amdgcn_sched_barrier(0);                                        \
  } while (0)

#pragma unroll 1
  for (int ci = 0; ci < NCI; ++ci) {
    const int c0 = cbase + ci * 128;
#pragma unroll
    for (int rt = 0; rt < 4; ++rt)
#pragma unroll
      for (int ct = 0; ct < 4; ++ct) {
        f32x4 z = {0.f, 0.f, 0.f, 0.f};
        acc[rt][ct] = z;
      }

    // 16 K-steps; ci*16 is a multiple of 4 so ring index == j.
#pragma unroll 1
    for (int kc4 = 0; kc4 < 4; ++kc4) {
      const int s = ci * 16 + kc4 * 4;
      PIPE_STEP(s + 0, 0);
      PIPE_STEP(s + 1, 1);
      PIPE_STEP(s + 2, 2);
      PIPE_STEP(s + 3, 3);
    }

    // ---- screen this 128-code tile. d' = 1 + csq - 2*dot (>0, bit-orderable)
    // Barriers here are lgkmcnt-only: prefetch DMAs stay in flight across
    // the screen (they target ring buffers the screen never touches).
    float cs1[4];
#pragma unroll
    for (int ct = 0; ct < 4; ++ct)
      cs1[ct] = 1.0f + csq[c0 + cOff + ct * 16 + l15];

    // min pass (C/D layout m89: col=lane&15, row=q*4+reg)
#pragma unroll
    for (int rt = 0; rt < 4; ++rt) {
#pragma unroll
      for (int reg = 0; reg < 4; ++reg) {
        float m = fmaf(-2.0f, acc[rt][0][reg], cs1[0]);
#pragma unroll
        for (int ct = 1; ct < 4; ++ct) {
          float d = fmaf(-2.0f, acc[rt][ct][reg], cs1[ct]);
          m = fminf(m, d);
        }
        unsigned mb = __float_as_uint(m);   // d'>0 -> bit order == value order
#pragma unroll
        for (int msk = 1; msk <= 8; msk <<= 1) {
          unsigned o = __shfl_xor(mb, msk, 64);
          mb = mb < o ? mb : o;
        }
        if (l15 == 0) atomicMin(&best[rOff + rt * 16 + q * 4 + reg], mb);
      }
    }
    asm volatile("s_waitcnt lgkmcnt(0)" ::: "memory");
    __builtin_amdgcn_sched_barrier(0);
    __builtin_amdgcn_s_barrier();
    __builtin_amdgcn_sched_barrier(0);

    // append pass vs prefix-min threshold (no trailing barrier needed: the
    // next touch of best/cnt/list is >=16 step-barriers away).
#pragma unroll
    for (int rt = 0; rt < 4; ++rt) {
#pragma unroll
      for (int reg = 0; reg < 4; ++reg) {
        const int rloc = rOff + rt * 16 + q * 4 + reg;
        const float thr = __uint_as_float(best[rloc]) + MARGIN;
#pragma unroll
        for (int ct = 0; ct < 4; ++ct) {
          float d = fmaf(-2.0f, acc[rt][ct][reg], cs1[ct]);
          if (d <= thr) {
            int pos2 = atomicAdd(&cnt_l[rloc], 1);
            if (pos2 < CAP)
              list_l[rloc * CAP + pos2] =
                  (unsigned short)(c0 + cOff + ct * 16 + l15);
          }
        }
      }
    }
  }
#undef PIPE_STEP

  __syncthreads();   // full drain: appends visible, phantom DMAs retired

  // per-quarter outputs: cnt (clamped, overflow flag survives u8), list, qmin.
  for (int i = tid; i < 128; i += 256) {
    int c = cnt_l[i];
    cnt_g[(size_t)(row0 + i) * 4 + qtr] = (unsigned char)(c > CAP ? CAP + 1 : c);
    bmin_g[(size_t)(row0 + i) * 4 + qtr] = best[i];
  }
  for (int i = tid; i < 128 * CAP; i += 256) {
    const int r = i / CAP, p = i % CAP;
    list_g[((size_t)(row0 + r) * 4 + qtr) * CAP + p] = list_l[i];
  }
}

// ---------------- exact distance, R1's bit-exact fmaf chain (both paths)
__device__ __forceinline__ float exact_dist(const float4* __restrict__ xr4,
                                            const float* __restrict__ cb,
                                            const float* __restrict__ csq,
                                            float xs, int idx) {
  const float4* cr4 = (const float4*)(cb + (size_t)idx * DD);
  float acc = 0.0f;
  for (int k4 = 0; k4 < DD / 4; ++k4) {     // sequential ascending k: R1 order
    float4 xv = xr4[k4];
    float4 cv = cr4[k4];
    acc = fmaf(xv.x, cv.x, acc);
    acc = fmaf(xv.y, cv.y, acc);
    acc = fmaf(xv.z, cv.z, acc);
    acc = fmaf(xv.w, cv.w, acc);
  }
  float t = xs - 2.0f * acc;
  return t + csq[idx];
}

// ---------------- phase 2 fused: exact rescore + straight-through gather +
// loss partial + idx-as-float. One wave per row. Quarters with qmin >
// gmin+MARGIN cannot hold the argmin or any exact tie (bf16 err <= MARGIN/2
// each way) -> skipped. Overflowed RELEVANT quarters exactly scanned (2048).
__global__ __launch_bounds__(256) void rescore_epilogue_kernel(
    const float* __restrict__ x, const float* __restrict__ cb,
    const float* __restrict__ xsq, const float* __restrict__ csq,
    const unsigned short* __restrict__ list,
    const unsigned char* __restrict__ cnt, const unsigned* __restrict__ bmin,
    float* __restrict__ out_q, float* __restrict__ out_idx_f,
    double* __restrict__ partials) {
  const int row = blockIdx.x * 4 + (threadIdx.x >> 6);
  const int lane = threadIdx.x & 63;
  const unsigned char* c4 = cnt + (size_t)row * 4;
  const unsigned* bm4 = bmin + (size_t)row * 4;
  const float xs = xsq[row];
  const float4* xr4 = (const float4*)(x + (size_t)row * DD);

  float qm[4];
  int n[4];
#pragma unroll
  for (int s = 0; s < 4; ++s) {
    qm[s] = __uint_as_float(bm4[s]);
    n[s] = c4[s];
  }
  const float gmin = fminf(fminf(qm[0], qm[1]), fminf(qm[2], qm[3]));
  const float cut = gmin + MARGIN;
  bool listed[4], scanq[4];
  int L = 0;
#pragma unroll
  for (int s = 0; s < 4; ++s) {
    const bool rel = (qm[s] <= cut);
    listed[s] = rel && (n[s] <= CAP);
    scanq[s] = rel && (n[s] > CAP);
    if (listed[s]) L += n[s];
  }
  if (L > 64) {   // pathological: exact-scan every relevant quarter
#pragma unroll
    for (int s = 0; s < 4; ++s)
      if (listed[s]) { listed[s] = false; scanq[s] = true; }
    L = 0;
  }

  unsigned long long bestv = ~0ULL;

  // listed candidates from relevant healthy quarters (lane-parallel, <=64)
  int myidx = -1;
  int base = 0;
#pragma unroll
  for (int s = 0; s < 4; ++s) {
    if (listed[s]) {
      if (myidx < 0 && lane >= base && lane < base + n[s])
        myidx = (int)list[((size_t)row * 4 + s) * CAP + (lane - base)];
      base += n[s];
    }
  }
  if (myidx >= 0) {
    float d = exact_dist(xr4, cb, csq, xs, myidx);
    bestv = ((unsigned long long)__float_as_uint(d) << 32) | (unsigned)myidx;
  }

  // relevant overflowed quarters: exact lane-strided scan of that quarter
#pragma unroll
  for (int s = 0; s < 4; ++s) {
    if (scanq[s]) {
      const int q0 = s * (KCODES / 4);
      for (int idx = q0 + lane; idx < q0 + KCODES / 4; idx += 64) {
        float d = exact_dist(xr4, cb, csq, xs, idx);
        unsigned long long pk =
            ((unsigned long long)__float_as_uint(d) << 32) | (unsigned)idx;
        if (pk < bestv) bestv = pk;
      }
    }
  }

#pragma unroll
  for (int s = 1; s <= 32; s <<= 1) {
    unsigned long long o = __shfl_xor(bestv, s, 64);
    if (o < bestv) bestv = o;
  }
  const int k = (int)(bestv & 0xffffffffu);

  // ---- fused epilogue. Bit-exact replica of the old 128-thread kernel:
  // lane handles float4 #lane (old wave0 thread) and #lane+64 (old wave1),
  // reduced as two independent 64-lane shuffle trees, summed at the end.
  const float4* qr = (const float4*)(cb + (size_t)k * DD);
  float4* orow = (float4*)(out_q + (size_t)row * DD);

  float4 xa = xr4[lane], qa = qr[lane];
  float dax = qa.x - xa.x, day = qa.y - xa.y, daz = qa.z - xa.z, daw = qa.w - xa.w;
  float4 oa;
  oa.x = xa.x + dax; oa.y = xa.y + day; oa.z = xa.z + daz; oa.w = xa.w + daw;
  orow[lane] = oa;
  double pa = (double)(dax * dax) + (double)(day * day) +
              (double)(daz * daz) + (double)(daw * daw);

  float4 xb = xr4[lane + 64], qb = qr[lane + 64];
  float dbx = qb.x - xb.x, dby = qb.y - xb.y, dbz = qb.z - xb.z, dbw = qb.w - xb.w;
  float4 ob;
  ob.x = xb.x + dbx; ob.y = xb.y + dby; ob.z = xb.z + dbz; ob.w = xb.w + dbw;
  orow[lane + 64] = ob;
  double pb = (double)(dbx * dbx) + (double)(dby * dby) +
              (double)(dbz * dbz) + (double)(dbw * dbw);

  for (int off = 32; off > 0; off >>= 1) pa += __shfl_down(pa, off, 64);
  for (int off = 32; off > 0; off >>= 1) pb += __shfl_down(pb, off, 64);
  if (lane == 0) {
    partials[row] = pa + pb;
    out_idx_f[row] = (float)k;
  }
}

// ---------------- reduce partials -> vq_loss
__global__ __launch_bounds__(256) void finalize_kernel(
    const double* __restrict__ partials, float* __restrict__ out_loss) {
  __shared__ double red[256];
  double s = 0.0;
  for (int i = threadIdx.x; i < NROWS; i += 256) s += partials[i];
  red[threadIdx.x] = s;
  __syncthreads();
  for (int st = 128; st > 0; st >>= 1) {
    if (threadIdx.x < st) red[threadIdx.x] += red[threadIdx.x + st];
    __syncthreads();
  }
  if (threadIdx.x == 0) {
    double mean = red[0] / ((double)NROWS * (double)DD);
    float cl = (float)mean;
    out_loss[0] = cl + 0.25f * cl;
  }
}

extern "C" void kernel_launch(void* const* d_in, const int* in_sizes, int n_in,
                              void* d_out, int out_size, void* d_ws,
                              size_t ws_size, hipStream_t stream) {
  const float* x = (const float*)d_in[0];
  const float* cb = (const float*)d_in[1];
  float* out = (float*)d_out;

  // ws layout: partials | csq | xsq | cnt(u8,4/row) | bmin(u32,4/row) | list
  char* ws = (char*)d_ws;
  double* partials = (double*)ws;                               // 262144 B
  float* csq = (float*)(ws + 262144);                           //  32768 B
  float* xsq = (float*)(ws + 262144 + 32768);                   // 131072 B
  unsigned char* cnt = (unsigned char*)(ws + 262144 + 32768 + 131072); // 131072 B
  unsigned* bmin = (unsigned*)(ws + 262144 + 32768 + 131072 + 131072); // 524288 B
  unsigned short* list =
      (unsigned short*)(ws + 262144 + 32768 + 131072 + 131072 + 524288); // 6.3 MB

  // bf16 copies live in d_out scratch (overwritten by fused epilogue later)
  bf16_t* cbbf = (bf16_t*)d_out;
  bf16_t* xbf = cbbf + (size_t)KCODES * DD;

  prep_kernel<<<KCODES / 4, 256, 0, stream>>>(cb, csq, cbbf, KCODES);
  prep_kernel<<<NROWS / 4, 256, 0, stream>>>(x, xsq, xbf, NROWS);
  coarse_kernel<<<1024, 256, 0, stream>>>(xbf, cbbf, csq, cnt, list, bmin);
  rescore_epilogue_kernel<<<NROWS / 4, 256, 0, stream>>>(
      x, cb, xsq, csq, list, cnt, bmin, out, out + 16777216 + 1, partials);
  finalize_kernel<<<1, 256, 0, stream>>>(partials, out + 16777216);
}

// Round 5
// 896.747 us; speedup vs baseline: 2.8116x; 1.1226x over previous
//
#include <hip/hip_runtime.h>

// VQ forward on MI355X — round 14: revert to R10's 2-barrier single-buffer
// structure, widen K-step to BK=64.
// x: [32768,512] fp32, codebook: [8192,512] fp32.
// d_out (fp32): [16.7M) quantized_st | [1] vq_loss | [32768] idx-as-float
//
// R13 post-mortem: pipelining arc refuted on hardware (540 -> 593 -> 622 as
// LDS grew 33->46->72KB and blocks/CU fell 4->3->2). Matches learn_hip
// m131-m141: counted-vmcnt/dbuf grafts are null-negative outside the
// 8-phase structure; implicit cross-block overlap (m114) was the real
// latency hider and LDS growth killed it. R14: R10 structure (single
// buffer, __syncthreads pair per K-step, 4 waves, 128x128 tile) with BK=64:
// half the barrier-pairs (128/block), 2x MFMA (32/wave) and 2x staging
// (32KB, 8 gld16/thread) per step, LDS 39.9KB -> 4 blocks/CU by LDS.
// New 8-slot XOR swizzle (slot^row&7; BK=64 row stride=128B would
// otherwise serialize per G4) with pre-swizzled global source (rule #21).
// K-order per (row,code) unchanged -> screen distances bit-identical ->
// candidate sets/rescore/outputs unchanged (absmax 0 since R1). bmin
// export + quarter-pruned rescore kept from R13.

#define NROWS 32768
#define KCODES 8192
#define DD 512
#define CAP 24
#define MARGIN 2.5e-4f

typedef __bf16 bf16_t;
typedef __bf16 bf16x8 __attribute__((ext_vector_type(8)));
typedef float f32x4 __attribute__((ext_vector_type(4)));

__device__ __forceinline__ void gld16(const bf16_t* g, bf16_t* l) {
  __builtin_amdgcn_global_load_lds(
      (const __attribute__((address_space(1))) void*)g,
      (__attribute__((address_space(3))) void*)l, 16, 0, 0);
}

// ---------------- fused: sum of fp32 squares per row (fp64 accumulate, fp32
// round — summation order identical since R9) + bf16 convert.
__global__ __launch_bounds__(256) void prep_kernel(const float* __restrict__ in,
                                                   float* __restrict__ out_sq,
                                                   bf16_t* __restrict__ outb,
                                                   int nrows) {
  const int wave = threadIdx.x >> 6;
  const int lane = threadIdx.x & 63;
  const int row = blockIdx.x * 4 + wave;
  if (row >= nrows) return;
  const float* p = in + (size_t)row * DD;
  double s = 0.0;
#pragma unroll
  for (int j = 0; j < DD / 64; ++j) {
    float v = p[j * 64 + lane];
    float sq = v * v;
    s += (double)sq;
  }
  for (int off = 32; off > 0; off >>= 1) s += __shfl_down(s, off, 64);
  if (lane == 0) out_sq[row] = (float)s;
  const float4* p4 = (const float4*)p;
  float4 a = p4[lane * 2];
  float4 b = p4[lane * 2 + 1];
  bf16x8 o = {(bf16_t)a.x, (bf16_t)a.y, (bf16_t)a.z, (bf16_t)a.w,
              (bf16_t)b.x, (bf16_t)b.y, (bf16_t)b.z, (bf16_t)b.w};
  *(bf16x8*)(outb + (size_t)row * DD + lane * 8) = o;
}

// ---------------- coarse: bf16 MFMA GEMM (16x16x32, BK=64 steps) +
// prefix-min margin screen. Block tile 128 rows x 128 codes, 4 waves each
// 64x64 (acc[4][4]). Single-buffer, 2 __syncthreads per K-step (R10 sync).
// LDS tile layout: [row][64 bf16], 16B chunk (row, slot s in 0..7) stored
// at slot s^(row&7) (8-way XOR: row stride 128B is bank-degenerate without
// it). Staged via linear gld16 with pre-swizzled GLOBAL source.
__global__ __launch_bounds__(256, 3) void coarse_kernel(
    const bf16_t* __restrict__ xbf, const bf16_t* __restrict__ cbbf,
    const float* __restrict__ csq, unsigned char* __restrict__ cnt_g,
    unsigned short* __restrict__ list_g, unsigned* __restrict__ bmin_g) {
  __shared__ bf16_t As[128 * 64];               // 16 KB
  __shared__ bf16_t Bs[128 * 64];               // 16 KB
  __shared__ unsigned best[128];                // fp32 bits of min dist (d'>0)
  __shared__ int cnt_l[128];
  __shared__ unsigned short list_l[128 * CAP];  // 6 KB

  const int tid = threadIdx.x;
  const int w = tid >> 6;
  const int lane = tid & 63;
  const int q = lane >> 4;           // quad: k-group q*8..q*8+7, C rows q*4+reg
  const int l15 = lane & 15;
  const int rOff = (w & 1) * 64;     // wave rows rOff..rOff+63
  const int cOff = (w >> 1) * 64;    // wave cols cOff..cOff+63

  // XCD-aware decode: consecutive blockIdx round-robin XCDs (grid 1024).
  // Each XCD pair owns one 2MB bf16 codebook quarter (L2-resident).
  const int bid = blockIdx.x;
  const int xcd = bid & 7;
  const int g = bid >> 3;                    // 0..127
  const int qtr = xcd >> 1;                  // 0..3
  const int rowblk = (xcd & 1) * 128 + g;    // 0..255, bijective
  const int row0 = rowblk * 128;
  const int cbase = qtr * (KCODES / 4);
  const int NCI = (KCODES / 4) / 128;        // 16 code tiles of 128

  for (int i = tid; i < 128; i += 256) { best[i] = 0xFFFFFFFFu; cnt_l[i] = 0; }

  // ---- staging (lane-fixed): per K-step 4 A-calls + 4 B-calls, each 256
  // threads x 16B = 4KB = 32 rows. Call c: row = c*32 + (tid>>3), stored
  // slot = tid&7 (LDS dest linear in tid: wave-uniform base + lane*16).
  // Global slot sg = (tid&7) ^ (row&7); c*32 = 0 mod 8 -> sg call-invariant.
  const int srow = tid >> 3;          // 0..31 (row within call)
  const int spos = tid & 7;           // stored slot
  const int sg = spos ^ (srow & 7);   // global slot (pre-swizzled source)
  const bf16_t *aG[4], *bG[4];
  bf16_t *aL[4], *bL[4];
#pragma unroll
  for (int c = 0; c < 4; ++c) {
    const int r = c * 32 + srow;
    aG[c] = xbf + (size_t)(row0 + r) * DD + sg * 8;
    bG[c] = cbbf + (size_t)(cbase + r) * DD + sg * 8;
    aL[c] = As + r * 64 + spos * 8;
    bL[c] = Bs + r * 64 + spos * 8;
  }

  // fragment read offsets (elements), k-substep 0; substep 1 at ^32
  // (slot bits {ks,q1,q0} ^ (row&7); ks is bit2 -> XOR 4*8 elements).
  int afofs[4], bfofs[4];
#pragma unroll
  for (int rt = 0; rt < 4; ++rt) {
    const int r = rOff + rt * 16 + l15;
    afofs[rt] = r * 64 + ((q ^ (r & 7)) << 3);
  }
#pragma unroll
  for (int ct = 0; ct < 4; ++ct) {
    const int r = cOff + ct * 16 + l15;
    bfofs[ct] = r * 64 + ((q ^ (r & 7)) << 3);
  }

  __syncthreads();   // best/cnt init visible

  f32x4 acc[4][4];

#pragma unroll 1
  for (int ci = 0; ci < NCI; ++ci) {
    const int c0 = cbase + ci * 128;
    const size_t cioff = (size_t)(ci * 128) * DD;
#pragma unroll
    for (int rt = 0; rt < 4; ++rt)
#pragma unroll
      for (int ct = 0; ct < 4; ++ct) {
        f32x4 z = {0.f, 0.f, 0.f, 0.f};
        acc[rt][ct] = z;
      }

#pragma unroll 1
    for (int kc = 0; kc < DD / 64; ++kc) {   // 8 K-steps of 64
      const int kb = kc * 64;
      __syncthreads();               // previous step's readers done
#pragma unroll
      for (int c = 0; c < 4; ++c) {
        gld16(aG[c] + kb, aL[c]);
        gld16(bG[c] + cioff + kb, bL[c]);
      }
      __syncthreads();               // vmcnt(0) drain -> tiles ready

      // k-substep 0 (k = kb+0..31): 16 MFMAs
      bf16x8 a0[4], b0[4];
#pragma unroll
      for (int rt = 0; rt < 4; ++rt) a0[rt] = *(const bf16x8*)&As[afofs[rt]];
#pragma unroll
      for (int ct = 0; ct < 4; ++ct) b0[ct] = *(const bf16x8*)&Bs[bfofs[ct]];
#pragma unroll
      for (int rt = 0; rt < 4; ++rt)
#pragma unroll
        for (int ct = 0; ct < 4; ++ct)
          acc[rt][ct] = __builtin_amdgcn_mfma_f32_16x16x32_bf16(
              a0[rt], b0[ct], acc[rt][ct], 0, 0, 0);

      // k-substep 1 (k = kb+32..63): 16 MFMAs
      bf16x8 a1[4], b1[4];
#pragma unroll
      for (int rt = 0; rt < 4; ++rt)
        a1[rt] = *(const bf16x8*)&As[afofs[rt] ^ 32];
#pragma unroll
      for (int ct = 0; ct < 4; ++ct)
        b1[ct] = *(const bf16x8*)&Bs[bfofs[ct] ^ 32];
#pragma unroll
      for (int rt = 0; rt < 4; ++rt)
#pragma unroll
        for (int ct = 0; ct < 4; ++ct)
          acc[rt][ct] = __builtin_amdgcn_mfma_f32_16x16x32_bf16(
              a1[rt], b1[ct], acc[rt][ct], 0, 0, 0);
    }

    // ---- screen this 128-code tile. d' = 1 + csq - 2*dot (>0, bit-orderable)
    float cs1[4];
#pragma unroll
    for (int ct = 0; ct < 4; ++ct)
      cs1[ct] = 1.0f + csq[c0 + cOff + ct * 16 + l15];

    // min pass (C/D layout m89: col=lane&15, row=q*4+reg)
#pragma unroll
    for (int rt = 0; rt < 4; ++rt) {
#pragma unroll
      for (int reg = 0; reg < 4; ++reg) {
        float m = fmaf(-2.0f, acc[rt][0][reg], cs1[0]);
#pragma unroll
        for (int ct = 1; ct < 4; ++ct) {
          float d = fmaf(-2.0f, acc[rt][ct][reg], cs1[ct]);
          m = fminf(m, d);
        }
        unsigned mb = __float_as_uint(m);   // d'>0 -> bit order == value order
#pragma unroll
        for (int msk = 1; msk <= 8; msk <<= 1) {
          unsigned o = __shfl_xor(mb, msk, 64);
          mb = mb < o ? mb : o;
        }
        if (l15 == 0) atomicMin(&best[rOff + rt * 16 + q * 4 + reg], mb);
      }
    }
    __syncthreads();

    // append pass vs prefix-min threshold (no trailing barrier: next touch
    // of best/cnt/list is >=16 K-step barriers away).
#pragma unroll
    for (int rt = 0; rt < 4; ++rt) {
#pragma unroll
      for (int reg = 0; reg < 4; ++reg) {
        const int rloc = rOff + rt * 16 + q * 4 + reg;
        const float thr = __uint_as_float(best[rloc]) + MARGIN;
#pragma unroll
        for (int ct = 0; ct < 4; ++ct) {
          float d = fmaf(-2.0f, acc[rt][ct][reg], cs1[ct]);
          if (d <= thr) {
            int pos2 = atomicAdd(&cnt_l[rloc], 1);
            if (pos2 < CAP)
              list_l[rloc * CAP + pos2] =
                  (unsigned short)(c0 + cOff + ct * 16 + l15);
          }
        }
      }
    }
  }

  __syncthreads();   // appends visible

  // per-quarter outputs: cnt (clamped, overflow flag survives u8), list, qmin.
  for (int i = tid; i < 128; i += 256) {
    int c = cnt_l[i];
    cnt_g[(size_t)(row0 + i) * 4 + qtr] = (unsigned char)(c > CAP ? CAP + 1 : c);
    bmin_g[(size_t)(row0 + i) * 4 + qtr] = best[i];
  }
  for (int i = tid; i < 128 * CAP; i += 256) {
    const int r = i / CAP, p = i % CAP;
    list_g[((size_t)(row0 + r) * 4 + qtr) * CAP + p] = list_l[i];
  }
}

// ---------------- exact distance, R1's bit-exact fmaf chain (both paths)
__device__ __forceinline__ float exact_dist(const float4* __restrict__ xr4,
                                            const float* __restrict__ cb,
                                            const float* __restrict__ csq,
                                            float xs, int idx) {
  const float4* cr4 = (const float4*)(cb + (size_t)idx * DD);
  float acc = 0.0f;
  for (int k4 = 0; k4 < DD / 4; ++k4) {     // sequential ascending k: R1 order
    float4 xv = xr4[k4];
    float4 cv = cr4[k4];
    acc = fmaf(xv.x, cv.x, acc);
    acc = fmaf(xv.y, cv.y, acc);
    acc = fmaf(xv.z, cv.z, acc);
    acc = fmaf(xv.w, cv.w, acc);
  }
  float t = xs - 2.0f * acc;
  return t + csq[idx];
}

// ---------------- phase 2 fused: exact rescore + straight-through gather +
// loss partial + idx-as-float. One wave per row. Quarters with qmin >
// gmin+MARGIN cannot hold the argmin or any exact tie (bf16 err <= MARGIN/2
// each way) -> skipped. Overflowed RELEVANT quarters exactly scanned (2048).
__global__ __launch_bounds__(256) void rescore_epilogue_kernel(
    const float* __restrict__ x, const float* __restrict__ cb,
    const float* __restrict__ xsq, const float* __restrict__ csq,
    const unsigned short* __restrict__ list,
    const unsigned char* __restrict__ cnt, const unsigned* __restrict__ bmin,
    float* __restrict__ out_q, float* __restrict__ out_idx_f,
    double* __restrict__ partials) {
  const int row = blockIdx.x * 4 + (threadIdx.x >> 6);
  const int lane = threadIdx.x & 63;
  const unsigned char* c4 = cnt + (size_t)row * 4;
  const unsigned* bm4 = bmin + (size_t)row * 4;
  const float xs = xsq[row];
  const float4* xr4 = (const float4*)(x + (size_t)row * DD);

  float qm[4];
  int n[4];
#pragma unroll
  for (int s = 0; s < 4; ++s) {
    qm[s] = __uint_as_float(bm4[s]);
    n[s] = c4[s];
  }
  const float gmin = fminf(fminf(qm[0], qm[1]), fminf(qm[2], qm[3]));
  const float cut = gmin + MARGIN;
  bool listed[4], scanq[4];
  int L = 0;
#pragma unroll
  for (int s = 0; s < 4; ++s) {
    const bool rel = (qm[s] <= cut);
    listed[s] = rel && (n[s] <= CAP);
    scanq[s] = rel && (n[s] > CAP);
    if (listed[s]) L += n[s];
  }
  if (L > 64) {   // pathological: exact-scan every relevant quarter
#pragma unroll
    for (int s = 0; s < 4; ++s)
      if (listed[s]) { listed[s] = false; scanq[s] = true; }
    L = 0;
  }

  unsigned long long bestv = ~0ULL;

  // listed candidates from relevant healthy quarters (lane-parallel, <=64)
  int myidx = -1;
  int base = 0;
#pragma unroll
  for (int s = 0; s < 4; ++s) {
    if (listed[s]) {
      if (myidx < 0 && lane >= base && lane < base + n[s])
        myidx = (int)list[((size_t)row * 4 + s) * CAP + (lane - base)];
      base += n[s];
    }
  }
  if (myidx >= 0) {
    float d = exact_dist(xr4, cb, csq, xs, myidx);
    bestv = ((unsigned long long)__float_as_uint(d) << 32) | (unsigned)myidx;
  }

  // relevant overflowed quarters: exact lane-strided scan of that quarter
#pragma unroll
  for (int s = 0; s < 4; ++s) {
    if (scanq[s]) {
      const int q0 = s * (KCODES / 4);
      for (int idx = q0 + lane; idx < q0 + KCODES / 4; idx += 64) {
        float d = exact_dist(xr4, cb, csq, xs, idx);
        unsigned long long pk =
            ((unsigned long long)__float_as_uint(d) << 32) | (unsigned)idx;
        if (pk < bestv) bestv = pk;
      }
    }
  }

#pragma unroll
  for (int s = 1; s <= 32; s <<= 1) {
    unsigned long long o = __shfl_xor(bestv, s, 64);
    if (o < bestv) bestv = o;
  }
  const int k = (int)(bestv & 0xffffffffu);

  // ---- fused epilogue. Bit-exact replica of the old 128-thread kernel:
  // lane handles float4 #lane (old wave0 thread) and #lane+64 (old wave1),
  // reduced as two independent 64-lane shuffle trees, summed at the end.
  const float4* qr = (const float4*)(cb + (size_t)k * DD);
  float4* orow = (float4*)(out_q + (size_t)row * DD);

  float4 xa = xr4[lane], qa = qr[lane];
  float dax = qa.x - xa.x, day = qa.y - xa.y, daz = qa.z - xa.z, daw = qa.w - xa.w;
  float4 oa;
  oa.x = xa.x + dax; oa.y = xa.y + day; oa.z = xa.z + daz; oa.w = xa.w + daw;
  orow[lane] = oa;
  double pa = (double)(dax * dax) + (double)(day * day) +
              (double)(daz * daz) + (double)(daw * daw);

  float4 xb = xr4[lane + 64], qb = qr[lane + 64];
  float dbx = qb.x - xb.x, dby = qb.y - xb.y, dbz = qb.z - xb.z, dbw = qb.w - xb.w;
  float4 ob;
  ob.x = xb.x + dbx; ob.y = xb.y + dby; ob.z = xb.z + dbz; ob.w = xb.w + dbw;
  orow[lane + 64] = ob;
  double pb = (double)(dbx * dbx) + (double)(dby * dby) +
              (double)(dbz * dbz) + (double)(dbw * dbw);

  for (int off = 32; off > 0; off >>= 1) pa += __shfl_down(pa, off, 64);
  for (int off = 32; off > 0; off >>= 1) pb += __shfl_down(pb, off, 64);
  if (lane == 0) {
    partials[row] = pa + pb;
    out_idx_f[row] = (float)k;
  }
}

// ---------------- reduce partials -> vq_loss
__global__ __launch_bounds__(256) void finalize_kernel(
    const double* __restrict__ partials, float* __restrict__ out_loss) {
  __shared__ double red[256];
  double s = 0.0;
  for (int i = threadIdx.x; i < NROWS; i += 256) s += partials[i];
  red[threadIdx.x] = s;
  __syncthreads();
  for (int st = 128; st > 0; st >>= 1) {
    if (threadIdx.x < st) red[threadIdx.x] += red[threadIdx.x + st];
    __syncthreads();
  }
  if (threadIdx.x == 0) {
    double mean = red[0] / ((double)NROWS * (double)DD);
    float cl = (float)mean;
    out_loss[0] = cl + 0.25f * cl;
  }
}

extern "C" void kernel_launch(void* const* d_in, const int* in_sizes, int n_in,
                              void* d_out, int out_size, void* d_ws,
                              size_t ws_size, hipStream_t stream) {
  const float* x = (const float*)d_in[0];
  const float* cb = (const float*)d_in[1];
  float* out = (float*)d_out;

  // ws layout: partials | csq | xsq | cnt(u8,4/row) | bmin(u32,4/row) | list
  char* ws = (char*)d_ws;
  double* partials = (double*)ws;                               // 262144 B
  float* csq = (float*)(ws + 262144);                           //  32768 B
  float* xsq = (float*)(ws + 262144 + 32768);                   // 131072 B
  unsigned char* cnt = (unsigned char*)(ws + 262144 + 32768 + 131072); // 131072 B
  unsigned* bmin = (unsigned*)(ws + 262144 + 32768 + 131072 + 131072); // 524288 B
  unsigned short* list =
      (unsigned short*)(ws + 262144 + 32768 + 131072 + 131072 + 524288); // 6.3 MB

  // bf16 copies live in d_out scratch (overwritten by fused epilogue later)
  bf16_t* cbbf = (bf16_t*)d_out;
  bf16_t* xbf = cbbf + (size_t)KCODES * DD;

  prep_kernel<<<KCODES / 4, 256, 0, stream>>>(cb, csq, cbbf, KCODES);
  prep_kernel<<<NROWS / 4, 256, 0, stream>>>(x, xsq, xbf, NROWS);
  coarse_kernel<<<1024, 256, 0, stream>>>(xbf, cbbf, csq, cnt, list, bmin);
  rescore_epilogue_kernel<<<NROWS / 4, 256, 0, stream>>>(
      x, cb, xsq, csq, list, cnt, bmin, out, out + 16777216 + 1, partials);
  finalize_kernel<<<1, 256, 0, stream>>>(partials, out + 16777216);
}

// Round 6
// 878.583 us; speedup vs baseline: 2.8697x; 1.0207x over previous
//
#include <hip/hip_runtime.h>

// VQ forward on MI355X — round 15: BK=128 (halve the drain count).
// x: [32768,512] fp32, codebook: [8192,512] fp32.
// d_out (fp32): [16.7M) quantized_st | [1] vq_loss | [32768] idx-as-float
//
// R14 post-mortem: BK=64 single-buffer = 511us coarse, MfmaUtil 23%. Per
// K-step: ~515cy MFMA vs ~600-900cy exposed vmcnt(0) drain; 2 blocks/CU
// (acc regs push true usage ~140) only half-hides it. R13 proved deep
// pipelines regress here, so R15 keeps the proven 2-barrier structure and
// halves the NUMBER of drains: BK=128. Per step 16 gld16/thread (64KB),
// 32 ds_read_b128/wave, 64 MFMA/wave; 64 drain events/block vs 128. LDS
// 71KB -> still 2 blocks/CU (m132's occupancy-loss mechanism absent).
// 16-slot layout, XOR swizzle slot^=(r&7) on BOTH staging source and
// fragment reads (same involution, rule #21). K-accumulation order per
// (row,code) unchanged (k ascending 0,32,...,480) -> screen distances
// bit-identical -> candidate sets/rescore/outputs unchanged (absmax 0
// since R1). Screen, rescore, prep, finalize untouched.

#define NROWS 32768
#define KCODES 8192
#define DD 512
#define CAP 24
#define MARGIN 2.5e-4f

typedef __bf16 bf16_t;
typedef __bf16 bf16x8 __attribute__((ext_vector_type(8)));
typedef float f32x4 __attribute__((ext_vector_type(4)));

__device__ __forceinline__ void gld16(const bf16_t* g, bf16_t* l) {
  __builtin_amdgcn_global_load_lds(
      (const __attribute__((address_space(1))) void*)g,
      (__attribute__((address_space(3))) void*)l, 16, 0, 0);
}

// ---------------- fused: sum of fp32 squares per row (fp64 accumulate, fp32
// round — summation order identical since R9) + bf16 convert.
__global__ __launch_bounds__(256) void prep_kernel(const float* __restrict__ in,
                                                   float* __restrict__ out_sq,
                                                   bf16_t* __restrict__ outb,
                                                   int nrows) {
  const int wave = threadIdx.x >> 6;
  const int lane = threadIdx.x & 63;
  const int row = blockIdx.x * 4 + wave;
  if (row >= nrows) return;
  const float* p = in + (size_t)row * DD;
  double s = 0.0;
#pragma unroll
  for (int j = 0; j < DD / 64; ++j) {
    float v = p[j * 64 + lane];
    float sq = v * v;
    s += (double)sq;
  }
  for (int off = 32; off > 0; off >>= 1) s += __shfl_down(s, off, 64);
  if (lane == 0) out_sq[row] = (float)s;
  const float4* p4 = (const float4*)p;
  float4 a = p4[lane * 2];
  float4 b = p4[lane * 2 + 1];
  bf16x8 o = {(bf16_t)a.x, (bf16_t)a.y, (bf16_t)a.z, (bf16_t)a.w,
              (bf16_t)b.x, (bf16_t)b.y, (bf16_t)b.z, (bf16_t)b.w};
  *(bf16x8*)(outb + (size_t)row * DD + lane * 8) = o;
}

// ---------------- coarse: bf16 MFMA GEMM (16x16x32, BK=128 steps) +
// prefix-min margin screen. Block tile 128 rows x 128 codes, 4 waves each
// 64x64 (acc[4][4]). Single-buffer, 2 __syncthreads per K-step.
// LDS tile layout: [row][128 bf16] = 16 slots of 16B; slot s stored at
// s^(r&7) (row stride 256B is bank-degenerate without it). Staged via
// linear gld16 (dest = base + tid*16B) with pre-swizzled GLOBAL source.
__global__ __launch_bounds__(256, 2) void coarse_kernel(
    const bf16_t* __restrict__ xbf, const bf16_t* __restrict__ cbbf,
    const float* __restrict__ csq, unsigned char* __restrict__ cnt_g,
    unsigned short* __restrict__ list_g, unsigned* __restrict__ bmin_g) {
  __shared__ bf16_t As[128 * 128];              // 32 KB
  __shared__ bf16_t Bs[128 * 128];              // 32 KB
  __shared__ unsigned best[128];                // fp32 bits of min dist (d'>0)
  __shared__ int cnt_l[128];
  __shared__ unsigned short list_l[128 * CAP];  // 6 KB

  const int tid = threadIdx.x;
  const int w = tid >> 6;
  const int lane = tid & 63;
  const int q = lane >> 4;           // quad: k-group q*8..q*8+7, C rows q*4+reg
  const int l15 = lane & 15;
  const int rOff = (w & 1) * 64;     // wave rows rOff..rOff+63
  const int cOff = (w >> 1) * 64;    // wave cols cOff..cOff+63

  // XCD-aware decode: consecutive blockIdx round-robin XCDs (grid 1024).
  // Each XCD pair owns one 2MB bf16 codebook quarter (L2-resident).
  const int bid = blockIdx.x;
  const int xcd = bid & 7;
  const int g = bid >> 3;                    // 0..127
  const int qtr = xcd >> 1;                  // 0..3
  const int rowblk = (xcd & 1) * 128 + g;    // 0..255, bijective
  const int row0 = rowblk * 128;
  const int cbase = qtr * (KCODES / 4);
  const int NCI = (KCODES / 4) / 128;        // 16 code tiles of 128

  for (int i = tid; i < 128; i += 256) { best[i] = 0xFFFFFFFFu; cnt_l[i] = 0; }

  // ---- staging (lane-fixed): per K-step 8 A-calls + 8 B-calls, each 256
  // threads x 16B = 4KB = 16 rows x 256B. Call c: row = c*16 + (tid>>4),
  // stored slot = tid&15 (LDS dest linear: element offset tid*8 + c*2048).
  // Global slot sg = (tid&15) ^ (row&7); row&7 = (tid>>4)&7 (c*16 == 0 mod 8).
  const int sxrow = tid >> 4;          // 0..15 (row within call)
  const int spos = tid & 15;           // stored slot
  const int sg = spos ^ (sxrow & 7);   // global slot (pre-swizzled source)
  const bf16_t* aGb = xbf + (size_t)(row0 + sxrow) * DD + sg * 8;
  const bf16_t* bGb = cbbf + (size_t)(cbase + sxrow) * DD + sg * 8;
  bf16_t* aLb = As + tid * 8;
  bf16_t* bLb = Bs + tid * 8;

  // fragment read bases: r = rOff/cOff + rt*16 + l15; element base r*128,
  // swizzle mask r&7 == l15&7 (rOff, rt*16 are multiples of 8).
  const int rm = l15 & 7;
  const int arb0 = (rOff + l15) * 128;
  const int brb0 = (cOff + l15) * 128;

  __syncthreads();   // best/cnt init visible

  f32x4 acc[4][4];

#pragma unroll 1
  for (int ci = 0; ci < NCI; ++ci) {
    const int c0 = cbase + ci * 128;
    const size_t cioff = (size_t)(ci * 128) * DD;
#pragma unroll
    for (int rt = 0; rt < 4; ++rt)
#pragma unroll
      for (int ct = 0; ct < 4; ++ct) {
        f32x4 z = {0.f, 0.f, 0.f, 0.f};
        acc[rt][ct] = z;
      }

#pragma unroll 1
    for (int kc = 0; kc < DD / 128; ++kc) {   // 4 K-steps of 128
      const int kb = kc * 128;
      __syncthreads();               // previous step's readers done
#pragma unroll
      for (int c = 0; c < 8; ++c) {
        gld16(aGb + kb + c * (16 * DD), aLb + c * 2048);
        gld16(bGb + cioff + kb + c * (16 * DD), bLb + c * 2048);
      }
      __syncthreads();               // vmcnt(0) drain -> tiles ready

      // 4 K=32 substeps, ascending k (accumulation order == R14/R10).
#pragma unroll
      for (int ks = 0; ks < 4; ++ks) {
        const int kqx = ((ks * 4 + q) ^ rm) << 3;   // swizzled slot, elems
        bf16x8 af[4], bfr[4];
#pragma unroll
        for (int rt = 0; rt < 4; ++rt)
          af[rt] = *(const bf16x8*)&As[arb0 + rt * (16 * 128) + kqx];
#pragma unroll
        for (int ct = 0; ct < 4; ++ct)
          bfr[ct] = *(const bf16x8*)&Bs[brb0 + ct * (16 * 128) + kqx];
#pragma unroll
        for (int rt = 0; rt < 4; ++rt)
#pragma unroll
          for (int ct = 0; ct < 4; ++ct)
            acc[rt][ct] = __builtin_amdgcn_mfma_f32_16x16x32_bf16(
                af[rt], bfr[ct], acc[rt][ct], 0, 0, 0);
      }
    }

    // ---- screen this 128-code tile. d' = 1 + csq - 2*dot (>0, bit-orderable)
    float cs1[4];
#pragma unroll
    for (int ct = 0; ct < 4; ++ct)
      cs1[ct] = 1.0f + csq[c0 + cOff + ct * 16 + l15];

    // min pass (C/D layout m89: col=lane&15, row=q*4+reg)
#pragma unroll
    for (int rt = 0; rt < 4; ++rt) {
#pragma unroll
      for (int reg = 0; reg < 4; ++reg) {
        float m = fmaf(-2.0f, acc[rt][0][reg], cs1[0]);
#pragma unroll
        for (int ct = 1; ct < 4; ++ct) {
          float d = fmaf(-2.0f, acc[rt][ct][reg], cs1[ct]);
          m = fminf(m, d);
        }
        unsigned mb = __float_as_uint(m);   // d'>0 -> bit order == value order
#pragma unroll
        for (int msk = 1; msk <= 8; msk <<= 1) {
          unsigned o = __shfl_xor(mb, msk, 64);
          mb = mb < o ? mb : o;
        }
        if (l15 == 0) atomicMin(&best[rOff + rt * 16 + q * 4 + reg], mb);
      }
    }
    __syncthreads();

    // append pass vs prefix-min threshold (no trailing barrier: next touch
    // of As/Bs is behind the next K-step's leading __syncthreads).
#pragma unroll
    for (int rt = 0; rt < 4; ++rt) {
#pragma unroll
      for (int reg = 0; reg < 4; ++reg) {
        const int rloc = rOff + rt * 16 + q * 4 + reg;
        const float thr = __uint_as_float(best[rloc]) + MARGIN;
#pragma unroll
        for (int ct = 0; ct < 4; ++ct) {
          float d = fmaf(-2.0f, acc[rt][ct][reg], cs1[ct]);
          if (d <= thr) {
            int pos2 = atomicAdd(&cnt_l[rloc], 1);
            if (pos2 < CAP)
              list_l[rloc * CAP + pos2] =
                  (unsigned short)(c0 + cOff + ct * 16 + l15);
          }
        }
      }
    }
  }

  __syncthreads();   // appends visible

  // per-quarter outputs: cnt (clamped, overflow flag survives u8), list, qmin.
  for (int i = tid; i < 128; i += 256) {
    int c = cnt_l[i];
    cnt_g[(size_t)(row0 + i) * 4 + qtr] = (unsigned char)(c > CAP ? CAP + 1 : c);
    bmin_g[(size_t)(row0 + i) * 4 + qtr] = best[i];
  }
  for (int i = tid; i < 128 * CAP; i += 256) {
    const int r = i / CAP, p = i % CAP;
    list_g[((size_t)(row0 + r) * 4 + qtr) * CAP + p] = list_l[i];
  }
}

// ---------------- exact distance, R1's bit-exact fmaf chain (both paths)
__device__ __forceinline__ float exact_dist(const float4* __restrict__ xr4,
                                            const float* __restrict__ cb,
                                            const float* __restrict__ csq,
                                            float xs, int idx) {
  const float4* cr4 = (const float4*)(cb + (size_t)idx * DD);
  float acc = 0.0f;
  for (int k4 = 0; k4 < DD / 4; ++k4) {     // sequential ascending k: R1 order
    float4 xv = xr4[k4];
    float4 cv = cr4[k4];
    acc = fmaf(xv.x, cv.x, acc);
    acc = fmaf(xv.y, cv.y, acc);
    acc = fmaf(xv.z, cv.z, acc);
    acc = fmaf(xv.w, cv.w, acc);
  }
  float t = xs - 2.0f * acc;
  return t + csq[idx];
}

// ---------------- phase 2 fused: exact rescore + straight-through gather +
// loss partial + idx-as-float. One wave per row. Quarters with qmin >
// gmin+MARGIN cannot hold the argmin or any exact tie (bf16 err <= MARGIN/2
// each way) -> skipped. Overflowed RELEVANT quarters exactly scanned (2048).
__global__ __launch_bounds__(256) void rescore_epilogue_kernel(
    const float* __restrict__ x, const float* __restrict__ cb,
    const float* __restrict__ xsq, const float* __restrict__ csq,
    const unsigned short* __restrict__ list,
    const unsigned char* __restrict__ cnt, const unsigned* __restrict__ bmin,
    float* __restrict__ out_q, float* __restrict__ out_idx_f,
    double* __restrict__ partials) {
  const int row = blockIdx.x * 4 + (threadIdx.x >> 6);
  const int lane = threadIdx.x & 63;
  const unsigned char* c4 = cnt + (size_t)row * 4;
  const unsigned* bm4 = bmin + (size_t)row * 4;
  const float xs = xsq[row];
  const float4* xr4 = (const float4*)(x + (size_t)row * DD);

  float qm[4];
  int n[4];
#pragma unroll
  for (int s = 0; s < 4; ++s) {
    qm[s] = __uint_as_float(bm4[s]);
    n[s] = c4[s];
  }
  const float gmin = fminf(fminf(qm[0], qm[1]), fminf(qm[2], qm[3]));
  const float cut = gmin + MARGIN;
  bool listed[4], scanq[4];
  int L = 0;
#pragma unroll
  for (int s = 0; s < 4; ++s) {
    const bool rel = (qm[s] <= cut);
    listed[s] = rel && (n[s] <= CAP);
    scanq[s] = rel && (n[s] > CAP);
    if (listed[s]) L += n[s];
  }
  if (L > 64) {   // pathological: exact-scan every relevant quarter
#pragma unroll
    for (int s = 0; s < 4; ++s)
      if (listed[s]) { listed[s] = false; scanq[s] = true; }
    L = 0;
  }

  unsigned long long bestv = ~0ULL;

  // listed candidates from relevant healthy quarters (lane-parallel, <=64)
  int myidx = -1;
  int base = 0;
#pragma unroll
  for (int s = 0; s < 4; ++s) {
    if (listed[s]) {
      if (myidx < 0 && lane >= base && lane < base + n[s])
        myidx = (int)list[((size_t)row * 4 + s) * CAP + (lane - base)];
      base += n[s];
    }
  }
  if (myidx >= 0) {
    float d = exact_dist(xr4, cb, csq, xs, myidx);
    bestv = ((unsigned long long)__float_as_uint(d) << 32) | (unsigned)myidx;
  }

  // relevant overflowed quarters: exact lane-strided scan of that quarter
#pragma unroll
  for (int s = 0; s < 4; ++s) {
    if (scanq[s]) {
      const int q0 = s * (KCODES / 4);
      for (int idx = q0 + lane; idx < q0 + KCODES / 4; idx += 64) {
        float d = exact_dist(xr4, cb, csq, xs, idx);
        unsigned long long pk =
            ((unsigned long long)__float_as_uint(d) << 32) | (unsigned)idx;
        if (pk < bestv) bestv = pk;
      }
    }
  }

#pragma unroll
  for (int s = 1; s <= 32; s <<= 1) {
    unsigned long long o = __shfl_xor(bestv, s, 64);
    if (o < bestv) bestv = o;
  }
  const int k = (int)(bestv & 0xffffffffu);

  // ---- fused epilogue. Bit-exact replica of the old 128-thread kernel:
  // lane handles float4 #lane (old wave0 thread) and #lane+64 (old wave1),
  // reduced as two independent 64-lane shuffle trees, summed at the end.
  const float4* qr = (const float4*)(cb + (size_t)k * DD);
  float4* orow = (float4*)(out_q + (size_t)row * DD);

  float4 xa = xr4[lane], qa = qr[lane];
  float dax = qa.x - xa.x, day = qa.y - xa.y, daz = qa.z - xa.z, daw = qa.w - xa.w;
  float4 oa;
  oa.x = xa.x + dax; oa.y = xa.y + day; oa.z = xa.z + daz; oa.w = xa.w + daw;
  orow[lane] = oa;
  double pa = (double)(dax * dax) + (double)(day * day) +
              (double)(daz * daz) + (double)(daw * daw);

  float4 xb = xr4[lane + 64], qb = qr[lane + 64];
  float dbx = qb.x - xb.x, dby = qb.y - xb.y, dbz = qb.z - xb.z, dbw = qb.w - xb.w;
  float4 ob;
  ob.x = xb.x + dbx; ob.y = xb.y + dby; ob.z = xb.z + dbz; ob.w = xb.w + dbw;
  orow[lane + 64] = ob;
  double pb = (double)(dbx * dbx) + (double)(dby * dby) +
              (double)(dbz * dbz) + (double)(dbw * dbw);

  for (int off = 32; off > 0; off >>= 1) pa += __shfl_down(pa, off, 64);
  for (int off = 32; off > 0; off >>= 1) pb += __shfl_down(pb, off, 64);
  if (lane == 0) {
    partials[row] = pa + pb;
    out_idx_f[row] = (float)k;
  }
}

// ---------------- reduce partials -> vq_loss
__global__ __launch_bounds__(256) void finalize_kernel(
    const double* __restrict__ partials, float* __restrict__ out_loss) {
  __shared__ double red[256];
  double s = 0.0;
  for (int i = threadIdx.x; i < NROWS; i += 256) s += partials[i];
  red[threadIdx.x] = s;
  __syncthreads();
  for (int st = 128; st > 0; st >>= 1) {
    if (threadIdx.x < st) red[threadIdx.x] += red[threadIdx.x + st];
    __syncthreads();
  }
  if (threadIdx.x == 0) {
    double mean = red[0] / ((double)NROWS * (double)DD);
    float cl = (float)mean;
    out_loss[0] = cl + 0.25f * cl;
  }
}

extern "C" void kernel_launch(void* const* d_in, const int* in_sizes, int n_in,
                              void* d_out, int out_size, void* d_ws,
                              size_t ws_size, hipStream_t stream) {
  const float* x = (const float*)d_in[0];
  const float* cb = (const float*)d_in[1];
  float* out = (float*)d_out;

  // ws layout: partials | csq | xsq | cnt(u8,4/row) | bmin(u32,4/row) | list
  char* ws = (char*)d_ws;
  double* partials = (double*)ws;                               // 262144 B
  float* csq = (float*)(ws + 262144);                           //  32768 B
  float* xsq = (float*)(ws + 262144 + 32768);                   // 131072 B
  unsigned char* cnt = (unsigned char*)(ws + 262144 + 32768 + 131072); // 131072 B
  unsigned* bmin = (unsigned*)(ws + 262144 + 32768 + 131072 + 131072); // 524288 B
  unsigned short* list =
      (unsigned short*)(ws + 262144 + 32768 + 131072 + 131072 + 524288); // 6.3 MB

  // bf16 copies live in d_out scratch (overwritten by fused epilogue later)
  bf16_t* cbbf = (bf16_t*)d_out;
  bf16_t* xbf = cbbf + (size_t)KCODES * DD;

  prep_kernel<<<KCODES / 4, 256, 0, stream>>>(cb, csq, cbbf, KCODES);
  prep_kernel<<<NROWS / 4, 256, 0, stream>>>(x, xsq, xbf, NROWS);
  coarse_kernel<<<1024, 256, 0, stream>>>(xbf, cbbf, csq, cnt, list, bmin);
  rescore_epilogue_kernel<<<NROWS / 4, 256, 0, stream>>>(
      x, cb, xsq, csq, list, cnt, bmin, out, out + 16777216 + 1, partials);
  finalize_kernel<<<1, 256, 0, stream>>>(partials, out + 16777216);
}

// Round 7
// 871.304 us; speedup vs baseline: 2.8937x; 1.0084x over previous
//
#include <hip/hip_runtime.h>

// VQ forward on MI355X — round 16: BK=128 with conflict-free split-half LDS
// layout (R14's proven 8-slot pattern per half) + merged prep launch.
// x: [32768,512] fp32, codebook: [8192,512] fp32.
// d_out (fp32): [16.7M) quantized_st | [1] vq_loss | [32768] idx-as-float
//
// R15 post-mortem: BK=128 drain-halving worked (511->461us) but
// SQ_LDS_BANK_CONFLICT went 7.1K -> 33.56M = 8 extra cyc per ds_read_b128
// (~55us/CU). The 16-slot/256B-stride swizzle broke R14's conflict-free
// property. R16: keep BK=128, but tiles stored as TWO half-tiles each in
// R14's exact layout (row stride 128B, 8 slots, slot^(r&7) on both staging
// source and read — the involution rule #21). Substep ks reads half ks>>1,
// XOR 32 elems for ks&1 — addressing per half is byte-identical to R14
// (measured ~0 conflicts). K-order ascending unchanged -> screen distances
// bit-identical -> candidates/rescore/outputs unchanged (absmax 0 since
// R1). Also merged the two prep launches (same per-row code, bit-exact).

#define NROWS 32768
#define KCODES 8192
#define DD 512
#define CAP 24
#define MARGIN 2.5e-4f

typedef __bf16 bf16_t;
typedef __bf16 bf16x8 __attribute__((ext_vector_type(8)));
typedef float f32x4 __attribute__((ext_vector_type(4)));

__device__ __forceinline__ void gld16(const bf16_t* g, bf16_t* l) {
  __builtin_amdgcn_global_load_lds(
      (const __attribute__((address_space(1))) void*)g,
      (__attribute__((address_space(3))) void*)l, 16, 0, 0);
}

// ---------------- fused prep for BOTH inputs in one launch: per-row sum of
// fp32 squares (fp64 accumulate, fp32 round — summation order identical
// since R9) + bf16 convert. Blocks [0, KCODES/4) -> codebook, rest -> x.
__global__ __launch_bounds__(256) void prep_kernel(
    const float* __restrict__ x, const float* __restrict__ cb,
    float* __restrict__ xsq, float* __restrict__ csq,
    bf16_t* __restrict__ xbf, bf16_t* __restrict__ cbbf) {
  const int wave = threadIdx.x >> 6;
  const int lane = threadIdx.x & 63;
  const float* in;
  float* osq;
  bf16_t* ob;
  int row;
  if (blockIdx.x < KCODES / 4) {
    in = cb; osq = csq; ob = cbbf;
    row = blockIdx.x * 4 + wave;
    if (row >= KCODES) return;
  } else {
    in = x; osq = xsq; ob = xbf;
    row = (blockIdx.x - KCODES / 4) * 4 + wave;
    if (row >= NROWS) return;
  }
  const float* p = in + (size_t)row * DD;
  double s = 0.0;
#pragma unroll
  for (int j = 0; j < DD / 64; ++j) {
    float v = p[j * 64 + lane];
    float sq = v * v;
    s += (double)sq;
  }
  for (int off = 32; off > 0; off >>= 1) s += __shfl_down(s, off, 64);
  if (lane == 0) osq[row] = (float)s;
  const float4* p4 = (const float4*)p;
  float4 a = p4[lane * 2];
  float4 b = p4[lane * 2 + 1];
  bf16x8 o = {(bf16_t)a.x, (bf16_t)a.y, (bf16_t)a.z, (bf16_t)a.w,
              (bf16_t)b.x, (bf16_t)b.y, (bf16_t)b.z, (bf16_t)b.w};
  *(bf16x8*)(ob + (size_t)row * DD + lane * 8) = o;
}

// ---------------- coarse: bf16 MFMA GEMM (16x16x32, BK=128 steps) +
// prefix-min margin screen. Block tile 128 rows x 128 codes, 4 waves each
// 64x64 (acc[4][4]). Single-buffer, 2 __syncthreads per K-step.
// LDS: per K-step the 128-wide tile is stored as two HALF-tiles
// [128 rows][64 bf16] in R14's conflict-free layout: 16B chunk (row, slot
// s in 0..7) at slot s^(r&7), row stride 128B. Staged via linear gld16
// (dest = half + j*2048 + tid*8 elems) with pre-swizzled GLOBAL source.
__global__ __launch_bounds__(256, 2) void coarse_kernel(
    const bf16_t* __restrict__ xbf, const bf16_t* __restrict__ cbbf,
    const float* __restrict__ csq, unsigned char* __restrict__ cnt_g,
    unsigned short* __restrict__ list_g, unsigned* __restrict__ bmin_g) {
  __shared__ bf16_t As[2][128 * 64];            // 2 x 16 KB
  __shared__ bf16_t Bs[2][128 * 64];            // 2 x 16 KB
  __shared__ unsigned best[128];                // fp32 bits of min dist (d'>0)
  __shared__ int cnt_l[128];
  __shared__ unsigned short list_l[128 * CAP];  // 6 KB

  const int tid = threadIdx.x;
  const int w = tid >> 6;
  const int lane = tid & 63;
  const int q = lane >> 4;           // quad: k-group q*8..q*8+7, C rows q*4+reg
  const int l15 = lane & 15;
  const int rOff = (w & 1) * 64;     // wave rows rOff..rOff+63
  const int cOff = (w >> 1) * 64;    // wave cols cOff..cOff+63

  // XCD-aware decode: consecutive blockIdx round-robin XCDs (grid 1024).
  // Each XCD pair owns one 2MB bf16 codebook quarter (L2-resident).
  const int bid = blockIdx.x;
  const int xcd = bid & 7;
  const int g = bid >> 3;                    // 0..127
  const int qtr = xcd >> 1;                  // 0..3
  const int rowblk = (xcd & 1) * 128 + g;    // 0..255, bijective
  const int row0 = rowblk * 128;
  const int cbase = qtr * (KCODES / 4);
  const int NCI = (KCODES / 4) / 128;        // 16 code tiles of 128

  for (int i = tid; i < 128; i += 256) { best[i] = 0xFFFFFFFFu; cnt_l[i] = 0; }

  // ---- staging (lane-fixed; R14 pattern per half): call (h, j): 256
  // threads x 16B = 4KB = 32 rows x 128B. row r = j*32 + (tid>>3), stored
  // slot = tid&7; LDS dest elem = j*2048 + tid*8 (linear: HW scatter).
  // Global slot sg = (tid&7) ^ (r&7); r&7 = (tid>>3)&7 (j*32 == 0 mod 8).
  const int srow = tid >> 3;           // 0..31 (row within call)
  const int spos = tid & 7;            // stored slot
  const int sg = spos ^ (srow & 7);    // global slot (pre-swizzled source)
  const bf16_t* aGb = xbf + (size_t)(row0 + srow) * DD + sg * 8;
  const bf16_t* bGb = cbbf + (size_t)(cbase + srow) * DD + sg * 8;

  // fragment read offsets per half (elements): r = rOff/cOff + rt*16 + l15,
  // base r*64 + ((q ^ (r&7))<<3); substep-within-half flips elem bit 5.
  const int rm = l15 & 7;
  int afb[4], bfb[4];
#pragma unroll
  for (int rt = 0; rt < 4; ++rt) {
    afb[rt] = (rOff + rt * 16 + l15) * 64 + ((q ^ rm) << 3);
    bfb[rt] = (cOff + rt * 16 + l15) * 64 + ((q ^ rm) << 3);
  }

  __syncthreads();   // best/cnt init visible

  f32x4 acc[4][4];

#pragma unroll 1
  for (int ci = 0; ci < NCI; ++ci) {
    const int c0 = cbase + ci * 128;
    const size_t cioff = (size_t)(ci * 128) * DD;
#pragma unroll
    for (int rt = 0; rt < 4; ++rt)
#pragma unroll
      for (int ct = 0; ct < 4; ++ct) {
        f32x4 z = {0.f, 0.f, 0.f, 0.f};
        acc[rt][ct] = z;
      }

#pragma unroll 1
    for (int kc = 0; kc < DD / 128; ++kc) {   // 4 K-steps of 128
      const int kb = kc * 128;
      __syncthreads();               // previous step's readers done
#pragma unroll
      for (int h = 0; h < 2; ++h)
#pragma unroll
        for (int j = 0; j < 4; ++j) {
          gld16(aGb + kb + h * 64 + j * (32 * DD), &As[h][j * 2048 + tid * 8]);
          gld16(bGb + cioff + kb + h * 64 + j * (32 * DD),
                &Bs[h][j * 2048 + tid * 8]);
        }
      __syncthreads();               // vmcnt(0) drain -> tiles ready

      // 4 K=32 substeps, ascending k: half h = ks>>1, sub = ks&1 (^32 elems).
#pragma unroll
      for (int ks = 0; ks < 4; ++ks) {
        const int h = ks >> 1;
        const int sx = (ks & 1) << 5;
        bf16x8 af[4], bfr[4];
#pragma unroll
        for (int rt = 0; rt < 4; ++rt)
          af[rt] = *(const bf16x8*)&As[h][afb[rt] ^ sx];
#pragma unroll
        for (int ct = 0; ct < 4; ++ct)
          bfr[ct] = *(const bf16x8*)&Bs[h][bfb[ct] ^ sx];
#pragma unroll
        for (int rt = 0; rt < 4; ++rt)
#pragma unroll
          for (int ct = 0; ct < 4; ++ct)
            acc[rt][ct] = __builtin_amdgcn_mfma_f32_16x16x32_bf16(
                af[rt], bfr[ct], acc[rt][ct], 0, 0, 0);
      }
    }

    // ---- screen this 128-code tile. d' = 1 + csq - 2*dot (>0, bit-orderable)
    float cs1[4];
#pragma unroll
    for (int ct = 0; ct < 4; ++ct)
      cs1[ct] = 1.0f + csq[c0 + cOff + ct * 16 + l15];

    // min pass (C/D layout m89: col=lane&15, row=q*4+reg)
#pragma unroll
    for (int rt = 0; rt < 4; ++rt) {
#pragma unroll
      for (int reg = 0; reg < 4; ++reg) {
        float m = fmaf(-2.0f, acc[rt][0][reg], cs1[0]);
#pragma unroll
        for (int ct = 1; ct < 4; ++ct) {
          float d = fmaf(-2.0f, acc[rt][ct][reg], cs1[ct]);
          m = fminf(m, d);
        }
        unsigned mb = __float_as_uint(m);   // d'>0 -> bit order == value order
#pragma unroll
        for (int msk = 1; msk <= 8; msk <<= 1) {
          unsigned o = __shfl_xor(mb, msk, 64);
          mb = mb < o ? mb : o;
        }
        if (l15 == 0) atomicMin(&best[rOff + rt * 16 + q * 4 + reg], mb);
      }
    }
    __syncthreads();

    // append pass vs prefix-min threshold (no trailing barrier: next touch
    // of As/Bs is behind the next K-step's leading __syncthreads).
#pragma unroll
    for (int rt = 0; rt < 4; ++rt) {
#pragma unroll
      for (int reg = 0; reg < 4; ++reg) {
        const int rloc = rOff + rt * 16 + q * 4 + reg;
        const float thr = __uint_as_float(best[rloc]) + MARGIN;
#pragma unroll
        for (int ct = 0; ct < 4; ++ct) {
          float d = fmaf(-2.0f, acc[rt][ct][reg], cs1[ct]);
          if (d <= thr) {
            int pos2 = atomicAdd(&cnt_l[rloc], 1);
            if (pos2 < CAP)
              list_l[rloc * CAP + pos2] =
                  (unsigned short)(c0 + cOff + ct * 16 + l15);
          }
        }
      }
    }
  }

  __syncthreads();   // appends visible

  // per-quarter outputs: cnt (clamped, overflow flag survives u8), list, qmin.
  for (int i = tid; i < 128; i += 256) {
    int c = cnt_l[i];
    cnt_g[(size_t)(row0 + i) * 4 + qtr] = (unsigned char)(c > CAP ? CAP + 1 : c);
    bmin_g[(size_t)(row0 + i) * 4 + qtr] = best[i];
  }
  for (int i = tid; i < 128 * CAP; i += 256) {
    const int r = i / CAP, p = i % CAP;
    list_g[((size_t)(row0 + r) * 4 + qtr) * CAP + p] = list_l[i];
  }
}

// ---------------- exact distance, R1's bit-exact fmaf chain (both paths)
__device__ __forceinline__ float exact_dist(const float4* __restrict__ xr4,
                                            const float* __restrict__ cb,
                                            const float* __restrict__ csq,
                                            float xs, int idx) {
  const float4* cr4 = (const float4*)(cb + (size_t)idx * DD);
  float acc = 0.0f;
  for (int k4 = 0; k4 < DD / 4; ++k4) {     // sequential ascending k: R1 order
    float4 xv = xr4[k4];
    float4 cv = cr4[k4];
    acc = fmaf(xv.x, cv.x, acc);
    acc = fmaf(xv.y, cv.y, acc);
    acc = fmaf(xv.z, cv.z, acc);
    acc = fmaf(xv.w, cv.w, acc);
  }
  float t = xs - 2.0f * acc;
  return t + csq[idx];
}

// ---------------- phase 2 fused: exact rescore + straight-through gather +
// loss partial + idx-as-float. One wave per row. Quarters with qmin >
// gmin+MARGIN cannot hold the argmin or any exact tie (bf16 err <= MARGIN/2
// each way) -> skipped. Overflowed RELEVANT quarters exactly scanned (2048).
__global__ __launch_bounds__(256) void rescore_epilogue_kernel(
    const float* __restrict__ x, const float* __restrict__ cb,
    const float* __restrict__ xsq, const float* __restrict__ csq,
    const unsigned short* __restrict__ list,
    const unsigned char* __restrict__ cnt, const unsigned* __restrict__ bmin,
    float* __restrict__ out_q, float* __restrict__ out_idx_f,
    double* __restrict__ partials) {
  const int row = blockIdx.x * 4 + (threadIdx.x >> 6);
  const int lane = threadIdx.x & 63;
  const unsigned char* c4 = cnt + (size_t)row * 4;
  const unsigned* bm4 = bmin + (size_t)row * 4;
  const float xs = xsq[row];
  const float4* xr4 = (const float4*)(x + (size_t)row * DD);

  float qm[4];
  int n[4];
#pragma unroll
  for (int s = 0; s < 4; ++s) {
    qm[s] = __uint_as_float(bm4[s]);
    n[s] = c4[s];
  }
  const float gmin = fminf(fminf(qm[0], qm[1]), fminf(qm[2], qm[3]));
  const float cut = gmin + MARGIN;
  bool listed[4], scanq[4];
  int L = 0;
#pragma unroll
  for (int s = 0; s < 4; ++s) {
    const bool rel = (qm[s] <= cut);
    listed[s] = rel && (n[s] <= CAP);
    scanq[s] = rel && (n[s] > CAP);
    if (listed[s]) L += n[s];
  }
  if (L > 64) {   // pathological: exact-scan every relevant quarter
#pragma unroll
    for (int s = 0; s < 4; ++s)
      if (listed[s]) { listed[s] = false; scanq[s] = true; }
    L = 0;
  }

  unsigned long long bestv = ~0ULL;

  // listed candidates from relevant healthy quarters (lane-parallel, <=64)
  int myidx = -1;
  int base = 0;
#pragma unroll
  for (int s = 0; s < 4; ++s) {
    if (listed[s]) {
      if (myidx < 0 && lane >= base && lane < base + n[s])
        myidx = (int)list[((size_t)row * 4 + s) * CAP + (lane - base)];
      base += n[s];
    }
  }
  if (myidx >= 0) {
    float d = exact_dist(xr4, cb, csq, xs, myidx);
    bestv = ((unsigned long long)__float_as_uint(d) << 32) | (unsigned)myidx;
  }

  // relevant overflowed quarters: exact lane-strided scan of that quarter
#pragma unroll
  for (int s = 0; s < 4; ++s) {
    if (scanq[s]) {
      const int q0 = s * (KCODES / 4);
      for (int idx = q0 + lane; idx < q0 + KCODES / 4; idx += 64) {
        float d = exact_dist(xr4, cb, csq, xs, idx);
        unsigned long long pk =
            ((unsigned long long)__float_as_uint(d) << 32) | (unsigned)idx;
        if (pk < bestv) bestv = pk;
      }
    }
  }

#pragma unroll
  for (int s = 1; s <= 32; s <<= 1) {
    unsigned long long o = __shfl_xor(bestv, s, 64);
    if (o < bestv) bestv = o;
  }
  const int k = (int)(bestv & 0xffffffffu);

  // ---- fused epilogue. Bit-exact replica of the old 128-thread kernel:
  // lane handles float4 #lane (old wave0 thread) and #lane+64 (old wave1),
  // reduced as two independent 64-lane shuffle trees, summed at the end.
  const float4* qr = (const float4*)(cb + (size_t)k * DD);
  float4* orow = (float4*)(out_q + (size_t)row * DD);

  float4 xa = xr4[lane], qa = qr[lane];
  float dax = qa.x - xa.x, day = qa.y - xa.y, daz = qa.z - xa.z, daw = qa.w - xa.w;
  float4 oa;
  oa.x = xa.x + dax; oa.y = xa.y + day; oa.z = xa.z + daz; oa.w = xa.w + daw;
  orow[lane] = oa;
  double pa = (double)(dax * dax) + (double)(day * day) +
              (double)(daz * daz) + (double)(daw * daw);

  float4 xb = xr4[lane + 64], qb = qr[lane + 64];
  float dbx = qb.x - xb.x, dby = qb.y - xb.y, dbz = qb.z - xb.z, dbw = qb.w - xb.w;
  float4 ob;
  ob.x = xb.x + dbx; ob.y = xb.y + dby; ob.z = xb.z + dbz; ob.w = xb.w + dbw;
  orow[lane + 64] = ob;
  double pb = (double)(dbx * dbx) + (double)(dby * dby) +
              (double)(dbz * dbz) + (double)(dbw * dbw);

  for (int off = 32; off > 0; off >>= 1) pa += __shfl_down(pa, off, 64);
  for (int off = 32; off > 0; off >>= 1) pb += __shfl_down(pb, off, 64);
  if (lane == 0) {
    partials[row] = pa + pb;
    out_idx_f[row] = (float)k;
  }
}

// ---------------- reduce partials -> vq_loss
__global__ __launch_bounds__(256) void finalize_kernel(
    const double* __restrict__ partials, float* __restrict__ out_loss) {
  __shared__ double red[256];
  double s = 0.0;
  for (int i = threadIdx.x; i < NROWS; i += 256) s += partials[i];
  red[threadIdx.x] = s;
  __syncthreads();
  for (int st = 128; st > 0; st >>= 1) {
    if (threadIdx.x < st) red[threadIdx.x] += red[threadIdx.x + st];
    __syncthreads();
  }
  if (threadIdx.x == 0) {
    double mean = red[0] / ((double)NROWS * (double)DD);
    float cl = (float)mean;
    out_loss[0] = cl + 0.25f * cl;
  }
}

extern "C" void kernel_launch(void* const* d_in, const int* in_sizes, int n_in,
                              void* d_out, int out_size, void* d_ws,
                              size_t ws_size, hipStream_t stream) {
  const float* x = (const float*)d_in[0];
  const float* cb = (const float*)d_in[1];
  float* out = (float*)d_out;

  // ws layout: partials | csq | xsq | cnt(u8,4/row) | bmin(u32,4/row) | list
  char* ws = (char*)d_ws;
  double* partials = (double*)ws;                               // 262144 B
  float* csq = (float*)(ws + 262144);                           //  32768 B
  float* xsq = (float*)(ws + 262144 + 32768);                   // 131072 B
  unsigned char* cnt = (unsigned char*)(ws + 262144 + 32768 + 131072); // 131072 B
  unsigned* bmin = (unsigned*)(ws + 262144 + 32768 + 131072 + 131072); // 524288 B
  unsigned short* list =
      (unsigned short*)(ws + 262144 + 32768 + 131072 + 131072 + 524288); // 6.3 MB

  // bf16 copies live in d_out scratch (overwritten by fused epilogue later)
  bf16_t* cbbf = (bf16_t*)d_out;
  bf16_t* xbf = cbbf + (size_t)KCODES * DD;

  prep_kernel<<<(KCODES + NROWS) / 4, 256, 0, stream>>>(x, cb, xsq, csq,
                                                        xbf, cbbf);
  coarse_kernel<<<1024, 256, 0, stream>>>(xbf, cbbf, csq, cnt, list, bmin);
  rescore_epilogue_kernel<<<NROWS / 4, 256, 0, stream>>>(
      x, cb, xsq, csq, list, cnt, bmin, out, out + 16777216 + 1, partials);
  finalize_kernel<<<1, 256, 0, stream>>>(partials, out + 16777216);
}